// Round 15
// baseline (423.044 us; speedup 1.0000x reference)
//
#include <hip/hip_runtime.h>
#include <hip/hip_fp16.h>

#define BB 32
#define NN 512
#define FIN 74
#define DD 140
#define DP 160            // padded d (zero-filled 140..159), multiple of 32
#define DF 128
#define LL 4
#define NEGV (-9e15f)
#define RST 148           // s_h2 stride (floats)

typedef __attribute__((ext_vector_type(8))) short bf16x8;
typedef __attribute__((ext_vector_type(4))) float f32x4;

__device__ inline ushort f2bf(float x) {
    union { float f; unsigned u; } v; v.f = x;
    unsigned r = (v.u + 0x7FFFu + ((v.u >> 16) & 1u)) >> 16;   // RNE
    return (ushort)r;
}
__device__ inline ushort f2h_bits(float x) {
    __half h = __float2half(x);
    union { __half h; ushort u; } c; c.h = h; return c.u;
}
__device__ inline float h2f_bits(ushort u) {
    union { __half h; ushort u; } c; c.u = u; return __half2float(c.h);
}

// ---------------------------------------------------------------------------
// prep adjacency: adjp[b,i,j] = fp16(exp(-(dist-mu)^2/dev) + a1), sign bit =
// (a1>0). a1 is exactly 0/1; exp term >= e^-16 ~ 1.1e-7 > fp16 min subnormal.
__global__ __launch_bounds__(256) void k_prepa(const float* __restrict__ adj1,
                                               const float* __restrict__ dist,
                                               const float* __restrict__ mu_p,
                                               const float* __restrict__ dev_p,
                                               ushort* __restrict__ adjp) {
    float mu = mu_p[0], rdev = 1.0f / dev_p[0];
    size_t base = ((size_t)blockIdx.x * 256 + threadIdx.x) * 4;
    float4 av = *reinterpret_cast<const float4*>(adj1 + base);
    float4 dv = *reinterpret_cast<const float4*>(dist + base);
    float aa[4] = {av.x, av.y, av.z, av.w};
    float dd[4] = {dv.x, dv.y, dv.z, dv.w};
    ushort o[4];
#pragma unroll
    for (int c = 0; c < 4; ++c) {
        float t = dd[c] - mu;
        float a2 = __expf(-t * t * rdev) + aa[c];
        ushort h = f2h_bits(a2);
        if (aa[c] > 0.f) h |= 0x8000u;
        o[c] = h;
    }
    uint2 pk;
    pk.x = (uint)o[0] | ((uint)o[1] << 16);
    pk.y = (uint)o[2] | ((uint)o[3] << 16);
    *reinterpret_cast<uint2*>(adjp + base) = pk;
}

// ---------------------------------------------------------------------------
// prep weights: Wwb[k][d][f] = bf16(Ww[k][d][f]) padded; ATb[k][d][d2] =
// bf16(A[k][d2][d]) padded (transposed for contiguous B-frag reads).
__global__ __launch_bounds__(256) void k_prepw(const float* __restrict__ Ww,
                                               const float* __restrict__ A,
                                               ushort* __restrict__ Wwb,
                                               ushort* __restrict__ ATb) {
    int k = blockIdx.y;
    int idx = blockIdx.x * 256 + threadIdx.x;     // over DP*DP = 25600
    int d = idx / DP, f = idx % DP;
    const float* Wk = Ww + (size_t)k * DD * DD;
    const float* Ak = A + (size_t)k * DD * DD;
    ushort wv = 0, av = 0;
    if (d < DD && f < DD) {
        wv = f2bf(Wk[d * DD + f]);
        av = f2bf(Ak[f * DD + d]);
    }
    Wwb[(size_t)k * DP * DP + idx] = wv;
    ATb[(size_t)k * DP * DP + idx] = av;
}

// ---------------------------------------------------------------------------
// embed: x[b,n,d] = sum_f c_hs[b,n,f] * We[d,f]; also emits x_bf (padded).
__global__ __launch_bounds__(256) void k_embed(const float* __restrict__ chs,
                                               const float* __restrict__ We,
                                               float* __restrict__ x,
                                               ushort* __restrict__ x_bf) {
    __shared__ float s_we[FIN * 144];
    __shared__ float s_in[32 * FIN];
    int bn0 = blockIdx.x * 32;
    int tid = threadIdx.x;
    for (int idx = tid; idx < DD * FIN; idx += 256) {
        int r = idx / FIN, c = idx % FIN;
        s_we[c * 144 + r] = We[idx];
    }
    for (int idx = tid; idx < 32 * FIN; idx += 256)
        s_in[idx] = chs[(size_t)bn0 * FIN + idx];
    __syncthreads();
    int d = tid;
    if (d < DD) {
        float acc[32];
#pragma unroll
        for (int r = 0; r < 32; ++r) acc[r] = 0.f;
        for (int f = 0; f < FIN; ++f) {
            float w = s_we[f * 144 + d];
#pragma unroll
            for (int r = 0; r < 32; ++r) acc[r] = fmaf(s_in[r * FIN + f], w, acc[r]);
        }
#pragma unroll
        for (int r = 0; r < 32; ++r) {
            x[(size_t)(bn0 + r) * DD + d] = acc[r];
            x_bf[(size_t)(bn0 + r) * DP + d] = f2bf(acc[r]);
        }
    } else if (d < DP) {
#pragma unroll
        for (int r = 0; r < 32; ++r) x_bf[(size_t)(bn0 + r) * DP + d] = 0;
    }
}

// ---------------------------------------------------------------------------
// wtrans via MFMA: h = x@Ww^T + Wb ; hA = h@A.  (layer 0 only)
__global__ __launch_bounds__(256) void k_wtrans(const ushort* __restrict__ x_bf,
                                                const ushort* __restrict__ Wwb,
                                                const ushort* __restrict__ ATb,
                                                const float* __restrict__ Wb,
                                                ushort* __restrict__ h_bf,
                                                ushort* __restrict__ hA_bf,
                                                ushort* __restrict__ hT_bf) {
    __shared__ __align__(16) ushort s_h[32][168];
    int bn0 = blockIdx.x * 32;
    int b = bn0 >> 9, n0 = bn0 & (NN - 1);
    int tid = threadIdx.x;
    int w = tid >> 6, l = tid & 63;
    int wm = w & 1, wc = w >> 1;
    int lr = l & 15, kg = l >> 4;
    const ushort* xrow = x_bf + (size_t)(bn0 + wm * 16 + lr) * DP;
    f32x4 acc[5];
#pragma unroll
    for (int nt = 0; nt < 5; ++nt) acc[nt] = (f32x4)(0.f);
    for (int f0 = 0; f0 < DP; f0 += 32) {
        bf16x8 a = *reinterpret_cast<const bf16x8*>(xrow + f0 + kg * 8);
#pragma unroll
        for (int nt = 0; nt < 5; ++nt) {
            int col = (wc * 5 + nt) * 16 + lr;
            bf16x8 bfr = *reinterpret_cast<const bf16x8*>(Wwb + (size_t)col * DP + f0 + kg * 8);
            acc[nt] = __builtin_amdgcn_mfma_f32_16x16x32_bf16(a, bfr, acc[nt], 0, 0, 0);
        }
    }
#pragma unroll
    for (int nt = 0; nt < 5; ++nt) {
        int col = (wc * 5 + nt) * 16 + lr;
        float bias = col < DD ? Wb[col] : 0.f;
#pragma unroll
        for (int r = 0; r < 4; ++r) {
            int rowl = wm * 16 + kg * 4 + r;
            float v = col < DD ? acc[nt][r] + bias : 0.f;
            ushort u = f2bf(v);
            s_h[rowl][col] = u;
            h_bf[(size_t)(bn0 + rowl) * DP + col] = u;
        }
        acc[nt] = (f32x4)(0.f);
    }
    __syncthreads();
    for (int f0 = 0; f0 < DP; f0 += 32) {
        bf16x8 a = *reinterpret_cast<const bf16x8*>(&s_h[wm * 16 + lr][f0 + kg * 8]);
#pragma unroll
        for (int nt = 0; nt < 5; ++nt) {
            int col = (wc * 5 + nt) * 16 + lr;
            bf16x8 bfr = *reinterpret_cast<const bf16x8*>(ATb + (size_t)col * DP + f0 + kg * 8);
            acc[nt] = __builtin_amdgcn_mfma_f32_16x16x32_bf16(a, bfr, acc[nt], 0, 0, 0);
        }
    }
#pragma unroll
    for (int nt = 0; nt < 5; ++nt) {
        int col = (wc * 5 + nt) * 16 + lr;
#pragma unroll
        for (int r = 0; r < 4; ++r)
            hA_bf[(size_t)(bn0 + wm * 16 + kg * 4 + r) * DP + col] = f2bf(acc[nt][r]);
    }
    if (tid < DP) {
        int d = tid;
        ushort tmp[32];
#pragma unroll
        for (int nn = 0; nn < 32; ++nn) tmp[nn] = s_h[nn][d];
        ushort* dst = hT_bf + ((size_t)b * DP + d) * NN + n0;
#pragma unroll
        for (int q = 0; q < 4; ++q)
            *reinterpret_cast<bf16x8*>(dst + q * 8) = *reinterpret_cast<const bf16x8*>(tmp + q * 8);
    }
}

// ---------------------------------------------------------------------------
// esym via MFMA, TRIANGLE grid (bi<=bj): e and adjp-mask are symmetric, so
// each off-diagonal tile is computed once and written twice (mirror via LDS
// transpose). Stats: direct row-sums (slot bj*2+wn) + mirror column-sums
// (slot bi*2+wm) from the SAME exp values. Diagonal blocks skip the mirror.
__global__ __launch_bounds__(256) void k_esym(const ushort* __restrict__ h_bf,
                                              const ushort* __restrict__ hA_bf,
                                              const ushort* __restrict__ adjp,
                                              ushort* __restrict__ e,
                                              float* __restrict__ Sp) {
    __shared__ ushort s_t[64 * 66];   // 8.4 KB transpose staging
    int b = blockIdx.y;
    int idx = blockIdx.x;             // 0..35 upper-triangle index
    int bi = 0;
    while (idx >= 8 - bi) { idx -= 8 - bi; ++bi; }
    int bj = bi + idx;
    int i0 = bi * 64, j0 = bj * 64;
    int w = threadIdx.x >> 6, l = threadIdx.x & 63;
    int wm = w & 1, wn = w >> 1;
    int lr = l & 15, kg = l >> 4;
    const ushort* hb = h_bf + (size_t)b * NN * DP;
    const ushort* ab = hA_bf + (size_t)b * NN * DP;
    f32x4 acc[2][2];
#pragma unroll
    for (int mt = 0; mt < 2; ++mt)
#pragma unroll
        for (int nt = 0; nt < 2; ++nt) acc[mt][nt] = (f32x4)(0.f);
    size_t moff[2], noff[2];
#pragma unroll
    for (int t = 0; t < 2; ++t) {
        moff[t] = (size_t)(i0 + wm * 32 + t * 16 + lr) * DP;
        noff[t] = (size_t)(j0 + wn * 32 + t * 16 + lr) * DP;
    }
    for (int d0 = 0; d0 < DP; d0 += 32) {
        int off = d0 + kg * 8;
        bf16x8 am[2], hm[2], hn[2], an[2];
#pragma unroll
        for (int t = 0; t < 2; ++t) {
            am[t] = *reinterpret_cast<const bf16x8*>(ab + moff[t] + off);
            hm[t] = *reinterpret_cast<const bf16x8*>(hb + moff[t] + off);
            hn[t] = *reinterpret_cast<const bf16x8*>(hb + noff[t] + off);
            an[t] = *reinterpret_cast<const bf16x8*>(ab + noff[t] + off);
        }
#pragma unroll
        for (int mt = 0; mt < 2; ++mt)
#pragma unroll
            for (int nt = 0; nt < 2; ++nt) {
                acc[mt][nt] = __builtin_amdgcn_mfma_f32_16x16x32_bf16(am[mt], hn[nt], acc[mt][nt], 0, 0, 0);
                acc[mt][nt] = __builtin_amdgcn_mfma_f32_16x16x32_bf16(hm[mt], an[nt], acc[mt][nt], 0, 0, 0);
            }
    }
    ushort* eb = e + (size_t)b * NN * NN;
    ushort eh[2][2][4];
#pragma unroll
    for (int mt = 0; mt < 2; ++mt) {
        int rbase = i0 + wm * 32 + mt * 16 + kg * 4;
#pragma unroll
        for (int nt = 0; nt < 2; ++nt) {
            int col = j0 + wn * 32 + nt * 16 + lr;
#pragma unroll
            for (int r = 0; r < 4; ++r) {
                ushort u = f2h_bits(acc[mt][nt][r]);
                eh[mt][nt][r] = u;
                eb[(size_t)(rbase + r) * NN + col] = u;
            }
        }
    }
    // exp values + masks (once; reused by both stat directions)
    const ushort* ap = adjp + (size_t)b * NN * NN + (size_t)i0 * NN + j0;
    float ev[2][2][4];
    bool mk[2][2][4];
#pragma unroll
    for (int mt = 0; mt < 2; ++mt)
#pragma unroll
        for (int nt = 0; nt < 2; ++nt) {
            int coll = wn * 32 + nt * 16 + lr;
#pragma unroll
            for (int r = 0; r < 4; ++r) {
                int rowl = wm * 32 + mt * 16 + kg * 4 + r;
                ev[mt][nt][r] = __expf(acc[mt][nt][r]);
                mk[mt][nt][r] = (ap[(size_t)rowl * NN + coll] & 0x8000u) != 0;
            }
        }
    // direct stats: row sums over this wave's 32-col slice -> slot bj*2+wn
    {
        int slot = bj * 2 + wn;
        float* Sp1 = Sp + (((size_t)b) * 16 + slot) * NN;
        float* Sp2 = Sp + (((size_t)BB + b) * 16 + slot) * NN;
#pragma unroll
        for (int mt = 0; mt < 2; ++mt) {
#pragma unroll
            for (int r = 0; r < 4; ++r) {
                float v1 = 0.f, v2 = 0.f;
#pragma unroll
                for (int nt = 0; nt < 2; ++nt) {
                    v2 += ev[mt][nt][r];
                    if (mk[mt][nt][r]) v1 += ev[mt][nt][r];
                }
#pragma unroll
                for (int off = 1; off < 16; off <<= 1) {
                    v1 += __shfl_xor(v1, off);
                    v2 += __shfl_xor(v2, off);
                }
                if (lr == 0) {
                    int rowl = wm * 32 + mt * 16 + kg * 4 + r;
                    Sp1[i0 + rowl] = v1;
                    Sp2[i0 + rowl] = v2;
                }
            }
        }
    }
    if (bi != bj) {
        // mirror stats: column sums (rows J, cols I wm-half) -> slot bi*2+wm
        int slot = bi * 2 + wm;
        float* Sp1 = Sp + (((size_t)b) * 16 + slot) * NN;
        float* Sp2 = Sp + (((size_t)BB + b) * 16 + slot) * NN;
#pragma unroll
        for (int nt = 0; nt < 2; ++nt) {
            float v1 = 0.f, v2 = 0.f;
#pragma unroll
            for (int mt = 0; mt < 2; ++mt)
#pragma unroll
                for (int r = 0; r < 4; ++r) {
                    v2 += ev[mt][nt][r];
                    if (mk[mt][nt][r]) v1 += ev[mt][nt][r];
                }
            v1 += __shfl_xor(v1, 16); v2 += __shfl_xor(v2, 16);
            v1 += __shfl_xor(v1, 32); v2 += __shfl_xor(v2, 32);
            if (kg == 0) {
                int rowm = j0 + wn * 32 + nt * 16 + lr;
                Sp1[rowm] = v1;
                Sp2[rowm] = v2;
            }
        }
        // mirror e-tile via LDS transpose
#pragma unroll
        for (int mt = 0; mt < 2; ++mt) {
#pragma unroll
            for (int nt = 0; nt < 2; ++nt) {
                int coll = wn * 32 + nt * 16 + lr;
#pragma unroll
                for (int r = 0; r < 4; ++r) {
                    int rowl = wm * 32 + mt * 16 + kg * 4 + r;
                    s_t[rowl * 66 + coll] = eh[mt][nt][r];
                }
            }
        }
        __syncthreads();
        int a = threadIdx.x >> 2, c0 = (threadIdx.x & 3) * 16;   // mirror row, col-seg
        ushort tmp[16];
#pragma unroll
        for (int q = 0; q < 16; ++q) tmp[q] = s_t[(c0 + q) * 66 + a];
        ushort* dst = eb + (size_t)(j0 + a) * NN + i0 + c0;
        *reinterpret_cast<bf16x8*>(dst) = *reinterpret_cast<const bf16x8*>(tmp);
        *reinterpret_cast<bf16x8*>(dst + 8) = *reinterpret_cast<const bf16x8*>(tmp + 8);
    }
}

// ---------------------------------------------------------------------------
// sred: reduce Sp 16-slot partials to reciprocal denominators ONCE.
__global__ __launch_bounds__(256) void k_sred(const float* __restrict__ Sp,
                                              float* __restrict__ Cr) {
    int b = blockIdx.y;
    int j = blockIdx.x * 256 + threadIdx.x;
    const float* Sp1 = Sp + ((size_t)b) * 16 * NN;
    const float* Sp2 = Sp + ((size_t)(BB + b)) * 16 * NN;
    float a1 = 0.f, a2 = 0.f;
#pragma unroll
    for (int jb = 0; jb < 16; ++jb) {
        a1 += Sp1[jb * NN + j];
        a2 += Sp2[jb * NN + j];
    }
    Cr[(size_t)b * NN + j] = 1.0f / a1;
    Cr[(size_t)(BB + b) * NN + j] = 1.0f / a2;
}

// ---------------------------------------------------------------------------
// hprime + gate + NEXT-LAYER wtrans, fused. 16 i-rows per block, 512 THREADS
// (8 waves = path p x col-quarter q, tiles {3,3,2,2}) -> 32 waves/CU (was 16):
// doubles resident waves to hide streaming latency. Build spreads 16x128
// elems over 512 threads (uint2). Epilogue tiles {2,2,1,1,1,1,1,1}.
__global__ __launch_bounds__(512, 8) void k_hprime(const ushort* __restrict__ e,
                                                const ushort* __restrict__ adjp,
                                                const ushort* __restrict__ hT_bf,
                                                const float* __restrict__ Cr,
                                                const float* __restrict__ gw,
                                                const float* __restrict__ gb,
                                                float* __restrict__ x,
                                                const ushort* __restrict__ Wwb2,
                                                const ushort* __restrict__ ATb2,
                                                const float* __restrict__ Wb2,
                                                int do_next,
                                                ushort* __restrict__ h2_bf,
                                                ushort* __restrict__ hA2_bf,
                                                ushort* __restrict__ hT2_bf) {
    __shared__ ushort s_att[2][2][4][16 * 40]; // [buf][path][sub][row*40+j] 20 KB
    __shared__ float s_C[2][NN];               // 4 KB (reciprocal denominators)
    __shared__ float s_h2[16][RST];            // 9.25 KB (path-1 hp tile)
    __shared__ float s_pz[8][16];
    __shared__ float s_px[4][16];
    // epilogue aliases (s_att dead after main loop): 2 x 16*168 ushorts = 10.75KB
    ushort* s_x  = &s_att[0][0][0][0];
    ushort* s_hh = s_x + 16 * 168;
    int b = blockIdx.y, i0 = blockIdx.x * 16;
    int tid = threadIdx.x;
    int w = tid >> 6, l = tid & 63;
    int p = w >> 2, q = w & 3;
    int ntb = (q < 2) ? q * 3 : 6 + (q - 2) * 2;
    int ncnt = (q < 2) ? 3 : 2;
    int lr = l & 15, kg = l >> 4;
    int ai = tid >> 5, aj4 = (tid & 31) * 4;   // row, j-offset within 128-chunk
    int sub = aj4 >> 5, jj = aj4 & 31;
    const ushort* e_row = e + (size_t)b * NN * NN + (size_t)(i0 + ai) * NN;
    const ushort* p_row = adjp + (size_t)b * NN * NN + (size_t)(i0 + ai) * NN;
    const ushort* hTb = hT_bf + (size_t)b * DP * NN;

    // issue all e/adjp loads up front (4 chunks x uint2 each)
    uint2 e_r[4], p_r[4];
#pragma unroll
    for (int c = 0; c < 4; ++c) {
        e_r[c] = *reinterpret_cast<const uint2*>(e_row + c * 128 + aj4);
        p_r[c] = *reinterpret_cast<const uint2*>(p_row + c * 128 + aj4);
    }
    float xq[3][4];
    if (p == 0) {
#pragma unroll
        for (int nt = 0; nt < 3; ++nt) {
            int col = (ntb + nt) * 16 + lr;
            bool ok = (nt < ncnt) && (col < DD);
#pragma unroll
            for (int r = 0; r < 4; ++r) {
                int row = kg * 4 + r;
                xq[nt][r] = ok ? x[((size_t)b * NN + i0 + row) * DD + col] : 0.f;
            }
        }
    }
    // stage reciprocal denominators (pre-reduced by k_sred)
    if (tid < NN) {
        s_C[0][tid] = Cr[(size_t)b * NN + tid];
        s_C[1][tid] = Cr[(size_t)(BB + b) * NN + tid];
    }

    auto build = [&](const uint2& ev2, const uint2& pv2, int cbase, int buf) {
        uint ew[2] = {ev2.x, ev2.y};
        uint pw[2] = {pv2.x, pv2.y};
        ushort o1[4], o2[4];
#pragma unroll
        for (int qq = 0; qq < 2; ++qq) {
            float ev[2] = {h2f_bits((ushort)(ew[qq] & 0xFFFFu)), h2f_bits((ushort)(ew[qq] >> 16))};
            ushort hb[2] = {(ushort)(pw[qq] & 0xFFFFu), (ushort)(pw[qq] >> 16)};
#pragma unroll
            for (int c2 = 0; c2 < 2; ++c2) {
                int idx = qq * 2 + c2;
                int jg = cbase + aj4 + idx;
                bool mask = (hb[c2] & 0x8000u) != 0;
                float a2 = h2f_bits((ushort)(hb[c2] & 0x7FFFu));
                float eexp = __expf(ev[c2]);
                float att1 = eexp * s_C[0][jg];
                float att2 = a2 * eexp * s_C[1][jg];
                o1[idx] = mask ? f2bf(att1) : (ushort)0;
                o2[idx] = f2bf(att2);
            }
        }
        uint2 w1, w2;
        w1.x = (uint)o1[0] | ((uint)o1[1] << 16); w1.y = (uint)o1[2] | ((uint)o1[3] << 16);
        w2.x = (uint)o2[0] | ((uint)o2[1] << 16); w2.y = (uint)o2[2] | ((uint)o2[3] << 16);
        *reinterpret_cast<uint2*>(&s_att[buf][0][sub][ai * 40 + jj]) = w1;
        *reinterpret_cast<uint2*>(&s_att[buf][1][sub][ai * 40 + jj]) = w2;
    };

    f32x4 acc[3];
#pragma unroll
    for (int nt = 0; nt < 3; ++nt) acc[nt] = (f32x4)(0.f);

    __syncthreads();           // s_C ready
    build(e_r[0], p_r[0], 0, 0);
    __syncthreads();
#pragma unroll
    for (int c = 0; c < 4; ++c) {
        int cb = c & 1, nb = cb ^ 1;
        if (c < 3) build(e_r[c + 1], p_r[c + 1], (c + 1) * 128, nb);
#pragma unroll
        for (int s4 = 0; s4 < 4; ++s4) {
            int j0 = c * 128 + s4 * 32;
            bf16x8 afr = *reinterpret_cast<const bf16x8*>(&s_att[cb][p][s4][lr * 40 + kg * 8]);
#pragma unroll
            for (int nt = 0; nt < 3; ++nt) {
                if (nt < ncnt) {
                    bf16x8 bfr = *reinterpret_cast<const bf16x8*>(
                        hTb + (size_t)((ntb + nt) * 16 + lr) * NN + j0 + kg * 8);
                    acc[nt] = __builtin_amdgcn_mfma_f32_16x16x32_bf16(afr, bfr, acc[nt], 0, 0, 0);
                }
            }
        }
        __syncthreads();
    }
    // relu + gate partials (wave-local complete j-sums)
    float z4[4] = {0.f, 0.f, 0.f, 0.f}, sx4[4] = {0.f, 0.f, 0.f, 0.f};
#pragma unroll
    for (int nt = 0; nt < 3; ++nt) {
        if (nt < ncnt) {
            int col = (ntb + nt) * 16 + lr;
            bool ok = col < DD;
            float g1 = ok ? gw[DD + col] : 0.f;
            float g0 = (ok && p == 0) ? gw[col] : 0.f;
#pragma unroll
            for (int r = 0; r < 4; ++r) {
                float hp = fmaxf(acc[nt][r], 0.f);
                acc[nt][r] = hp;
                z4[r] = fmaf(g1, hp, z4[r]);
                if (p == 0) sx4[r] = fmaf(g0, xq[nt][r], sx4[r]);
            }
        }
    }
#pragma unroll
    for (int off = 1; off < 16; off <<= 1) {
#pragma unroll
        for (int r = 0; r < 4; ++r) {
            z4[r] += __shfl_xor(z4[r], off);
            if (p == 0) sx4[r] += __shfl_xor(sx4[r], off);
        }
    }
    if (lr == 0) {
#pragma unroll
        for (int r = 0; r < 4; ++r) {
            s_pz[w][kg * 4 + r] = z4[r];
            if (p == 0) s_px[w][kg * 4 + r] = sx4[r];
        }
    }
    if (p == 1) {
#pragma unroll
        for (int nt = 0; nt < 3; ++nt) {
            if (nt < ncnt) {
                int col = (ntb + nt) * 16 + lr;
#pragma unroll
                for (int r = 0; r < 4; ++r)
                    s_h2[kg * 4 + r][col] = acc[nt][r];
            }
        }
    }
    __syncthreads();
    if (p == 0) {
        float gbv = gb[0];
#pragma unroll
        for (int r = 0; r < 4; ++r) {
            int row = kg * 4 + r;
            float sx = s_px[0][row] + s_px[1][row] + s_px[2][row] + s_px[3][row];
            float z1 = s_pz[0][row] + s_pz[1][row] + s_pz[2][row] + s_pz[3][row];
            float z2 = s_pz[4][row] + s_pz[5][row] + s_pz[6][row] + s_pz[7][row];
            float c1 = 1.f / (1.f + __expf(-(sx + z1 + gbv)));
            float c2 = 1.f / (1.f + __expf(-(sx + z2 + gbv)));
#pragma unroll
            for (int nt = 0; nt < 3; ++nt) {
                if (nt < ncnt) {
                    int col = (ntb + nt) * 16 + lr;
                    if (col < DD) {
                        float xnew = (c2 - c1) * xq[nt][r] + (1.f - c2) * s_h2[row][col]
                                   - (1.f - c1) * acc[nt][r];
                        size_t bn = (size_t)b * NN + i0 + row;
                        x[bn * DD + col] = xnew;
                        s_x[row * 168 + col] = f2bf(xnew);
                    }
                }
            }
        }
    } else if (do_next) {
        // zero-fill s_x pad cols 140..159 (16 rows x 20 cols = 320)
        for (int idx = tid - 256; idx < 320; idx += 256) {
            if (idx >= 0) {
                int row = idx / 20, col = DD + idx % 20;
                s_x[row * 168 + col] = 0;
            }
        }
    }
    if (do_next) {
        __syncthreads();       // s_x complete
        int t0 = (w < 2) ? w * 2 : w + 2;
        int ecnt = (w < 2) ? 2 : 1;
        f32x4 acc2[2];
#pragma unroll
        for (int qq = 0; qq < 2; ++qq) acc2[qq] = (f32x4)(0.f);
        // GEMM1: h = xnew @ Ww2^T (+Wb2)
        for (int f0 = 0; f0 < DP; f0 += 32) {
            bf16x8 a = *reinterpret_cast<const bf16x8*>(&s_x[lr * 168 + f0 + kg * 8]);
#pragma unroll
            for (int qq = 0; qq < 2; ++qq) {
                if (qq < ecnt) {
                    int col = (t0 + qq) * 16 + lr;
                    bf16x8 bfr = *reinterpret_cast<const bf16x8*>(Wwb2 + (size_t)col * DP + f0 + kg * 8);
                    acc2[qq] = __builtin_amdgcn_mfma_f32_16x16x32_bf16(a, bfr, acc2[qq], 0, 0, 0);
                }
            }
        }
#pragma unroll
        for (int qq = 0; qq < 2; ++qq) {
            if (qq < ecnt) {
                int col = (t0 + qq) * 16 + lr;
                float bias = col < DD ? Wb2[col] : 0.f;
#pragma unroll
                for (int r = 0; r < 4; ++r) {
                    int row = kg * 4 + r;
                    float v = col < DD ? acc2[qq][r] + bias : 0.f;
                    ushort u = f2bf(v);
                    s_hh[row * 168 + col] = u;
                    h2_bf[((size_t)b * NN + i0 + row) * DP + col] = u;
                }
                acc2[qq] = (f32x4)(0.f);
            }
        }
        __syncthreads();       // s_hh complete
        // GEMM2: hA = h @ A2
        for (int f0 = 0; f0 < DP; f0 += 32) {
            bf16x8 a = *reinterpret_cast<const bf16x8*>(&s_hh[lr * 168 + f0 + kg * 8]);
#pragma unroll
            for (int qq = 0; qq < 2; ++qq) {
                if (qq < ecnt) {
                    int col = (t0 + qq) * 16 + lr;
                    bf16x8 bfr = *reinterpret_cast<const bf16x8*>(ATb2 + (size_t)col * DP + f0 + kg * 8);
                    acc2[qq] = __builtin_amdgcn_mfma_f32_16x16x32_bf16(a, bfr, acc2[qq], 0, 0, 0);
                }
            }
        }
#pragma unroll
        for (int qq = 0; qq < 2; ++qq) {
            if (qq < ecnt) {
                int col = (t0 + qq) * 16 + lr;
#pragma unroll
                for (int r = 0; r < 4; ++r)
                    hA2_bf[((size_t)b * NN + i0 + kg * 4 + r) * DP + col] = f2bf(acc2[qq][r]);
            }
        }
        // hT for next layer (16 columns i0..i0+16)
        if (tid < DP) {
            int d = tid;
            ushort tmp[16];
#pragma unroll
            for (int nn = 0; nn < 16; ++nn) tmp[nn] = s_hh[nn * 168 + d];
            ushort* dst = hT2_bf + ((size_t)b * DP + d) * NN + i0;
            *reinterpret_cast<bf16x8*>(dst) = *reinterpret_cast<const bf16x8*>(tmp);
            *reinterpret_cast<bf16x8*>(dst + 8) = *reinterpret_cast<const bf16x8*>(tmp + 8);
        }
    }
}

// ---------------------------------------------------------------------------
// readout: g[b,d] = sum_n x[b,n,d] * valid[b,n]
__global__ __launch_bounds__(256) void k_readout(const float* __restrict__ x,
                                                 const float* __restrict__ valid,
                                                 float* __restrict__ g) {
    int b = blockIdx.x;
    int t = threadIdx.x;
    if (t < DD) {
        float acc = 0.f;
        for (int n = 0; n < NN; ++n)
            acc = fmaf(x[((size_t)b * NN + n) * DD + t], valid[b * NN + n], acc);
        g[b * DD + t] = acc;
    }
}

// ---------------------------------------------------------------------------
// tiny MLP head: relu x3 + sigmoid
__global__ __launch_bounds__(128) void k_mlp(const float* __restrict__ g,
                                             const float* __restrict__ w0, const float* __restrict__ b0,
                                             const float* __restrict__ w1, const float* __restrict__ b1,
                                             const float* __restrict__ w2, const float* __restrict__ b2,
                                             const float* __restrict__ w3, const float* __restrict__ b3,
                                             float* __restrict__ out) {
    __shared__ float s0[DD];
    __shared__ float s1[DF];
    __shared__ float s2[DF];
    __shared__ float s_part[2];
    int b = blockIdx.x, t = threadIdx.x;
    for (int i = t; i < DD; i += 128) s0[i] = g[b * DD + i];
    __syncthreads();
    float acc = b0[t];
    for (int dd2 = 0; dd2 < DD; ++dd2) acc = fmaf(s0[dd2], w0[dd2 * DF + t], acc);
    s1[t] = fmaxf(acc, 0.f);
    __syncthreads();
    acc = b1[t];
    for (int dd2 = 0; dd2 < DF; ++dd2) acc = fmaf(s1[dd2], w1[dd2 * DF + t], acc);
    s2[t] = fmaxf(acc, 0.f);
    __syncthreads();
    acc = b2[t];
    for (int dd2 = 0; dd2 < DF; ++dd2) acc = fmaf(s2[dd2], w2[dd2 * DF + t], acc);
    float h3 = fmaxf(acc, 0.f);
    float p = h3 * w3[t];
#pragma unroll
    for (int off = 32; off > 0; off >>= 1) p += __shfl_down(p, off);
    if ((t & 63) == 0) s_part[t >> 6] = p;
    __syncthreads();
    if (t == 0) {
        float s = s_part[0] + s_part[1] + b3[0];
        out[b] = 1.f / (1.f + __expf(-s));
    }
}

// ---------------------------------------------------------------------------
extern "C" void kernel_launch(void* const* d_in, const int* in_sizes, int n_in,
                              void* d_out, int out_size, void* d_ws, size_t ws_size,
                              hipStream_t stream) {
    const float* chs   = (const float*)d_in[0];
    const float* adj1  = (const float*)d_in[1];
    const float* dist  = (const float*)d_in[2];
    const float* valid = (const float*)d_in[3];
    const float* We    = (const float*)d_in[4];
    const float* Ww    = (const float*)d_in[5];
    const float* Wb    = (const float*)d_in[6];
    const float* A     = (const float*)d_in[7];
    const float* gw    = (const float*)d_in[8];
    const float* gb    = (const float*)d_in[9];
    const float* mu    = (const float*)d_in[10];
    const float* dev   = (const float*)d_in[11];
    const float* w0    = (const float*)d_in[12];
    const float* b0    = (const float*)d_in[13];
    const float* w1    = (const float*)d_in[14];
    const float* b1    = (const float*)d_in[15];
    const float* w2    = (const float*)d_in[16];
    const float* b2    = (const float*)d_in[17];
    const float* w3    = (const float*)d_in[18];
    const float* b3    = (const float*)d_in[19];
    float* out = (float*)d_out;

    const size_t SX  = (size_t)BB * NN * DD;
    const size_t SNN = (size_t)BB * NN * NN;
    const size_t SBF = (size_t)BB * NN * DP;
    const size_t SSP = (size_t)2 * BB * 16 * NN;   // stats partials
    float* ws  = (float*)d_ws;
    float* x   = ws;
    float* Sp  = x + SX;
    float* Cr  = Sp + SSP;                         // 2*BB*NN reciprocals
    float* g   = Cr + (size_t)2 * BB * NN;
    ushort* hset0  = (ushort*)(g + BB * DD);      // h, hA, hT (set 0)
    ushort* hset1  = hset0 + 3 * SBF;             // h, hA, hT (set 1)
    ushort* x_bf   = hset1 + 3 * SBF;
    ushort* Wwb    = x_bf + SBF;
    ushort* ATb    = Wwb + (size_t)LL * DP * DP;
    ushort* adjp   = ATb + (size_t)LL * DP * DP;  // BB*NN*NN fp16 (signed)
    ushort* e_h    = adjp + SNN;                  // BB*NN*NN fp16

    k_prepa<<<SNN / 1024, 256, 0, stream>>>(adj1, dist, mu, dev, adjp);
    k_prepw<<<dim3(DP * DP / 256, LL), 256, 0, stream>>>(Ww, A, Wwb, ATb);
    k_embed<<<BB * NN / 32, 256, 0, stream>>>(chs, We, x, x_bf);

    // layer-0 transforms
    k_wtrans<<<BB * NN / 32, 256, 0, stream>>>(x_bf, Wwb, ATb, Wb,
                                               hset0, hset0 + SBF, hset0 + 2 * SBF);

    for (int k = 0; k < LL; ++k) {
        ushort* cur = (k & 1) ? hset1 : hset0;
        ushort* nxt = (k & 1) ? hset0 : hset1;
        int kn = (k < LL - 1) ? k + 1 : k;
        const float* gwk = gw + (size_t)k * 2 * DD;
        const float* gbk = gb + k;
        k_esym<<<dim3(36, BB), 256, 0, stream>>>(cur, cur + SBF, adjp, e_h, Sp);
        k_sred<<<dim3(NN / 256, BB), 256, 0, stream>>>(Sp, Cr);
        k_hprime<<<dim3(NN / 16, BB), 512, 0, stream>>>(
            e_h, adjp, cur + 2 * SBF, Cr, gwk, gbk, x,
            Wwb + (size_t)kn * DP * DP, ATb + (size_t)kn * DP * DP, Wb + (size_t)kn * DD,
            (k < LL - 1) ? 1 : 0,
            nxt, nxt + SBF, nxt + 2 * SBF);
    }

    k_readout<<<BB, 256, 0, stream>>>(x, valid, g);
    k_mlp<<<BB, 128, 0, stream>>>(g, w0, b0, w1, b1, w2, b2, w3, b3, out);
}

// Round 16
// 413.810 us; speedup vs baseline: 1.0223x; 1.0223x over previous
//
#include <hip/hip_runtime.h>
#include <hip/hip_fp16.h>

#define BB 32
#define NN 512
#define FIN 74
#define DD 140
#define DP 160            // padded d (zero-filled 140..159), multiple of 32
#define DF 128
#define LL 4
#define NEGV (-9e15f)
#define RST 148           // s_h2 stride (floats)

typedef __attribute__((ext_vector_type(8))) short bf16x8;
typedef __attribute__((ext_vector_type(4))) float f32x4;

__device__ inline ushort f2bf(float x) {
    union { float f; unsigned u; } v; v.f = x;
    unsigned r = (v.u + 0x7FFFu + ((v.u >> 16) & 1u)) >> 16;   // RNE
    return (ushort)r;
}
__device__ inline ushort f2h_bits(float x) {
    __half h = __float2half(x);
    union { __half h; ushort u; } c; c.h = h; return c.u;
}
__device__ inline float h2f_bits(ushort u) {
    union { __half h; ushort u; } c; c.u = u; return __half2float(c.h);
}

// ---------------------------------------------------------------------------
// prep adjacency: adjp[b,i,j] = fp16(exp(-(dist-mu)^2/dev) + a1), sign bit =
// (a1>0). a1 is exactly 0/1; exp term >= e^-16 ~ 1.1e-7 > fp16 min subnormal.
__global__ __launch_bounds__(256) void k_prepa(const float* __restrict__ adj1,
                                               const float* __restrict__ dist,
                                               const float* __restrict__ mu_p,
                                               const float* __restrict__ dev_p,
                                               ushort* __restrict__ adjp) {
    float mu = mu_p[0], rdev = 1.0f / dev_p[0];
    size_t base = ((size_t)blockIdx.x * 256 + threadIdx.x) * 4;
    float4 av = *reinterpret_cast<const float4*>(adj1 + base);
    float4 dv = *reinterpret_cast<const float4*>(dist + base);
    float aa[4] = {av.x, av.y, av.z, av.w};
    float dd[4] = {dv.x, dv.y, dv.z, dv.w};
    ushort o[4];
#pragma unroll
    for (int c = 0; c < 4; ++c) {
        float t = dd[c] - mu;
        float a2 = __expf(-t * t * rdev) + aa[c];
        ushort h = f2h_bits(a2);
        if (aa[c] > 0.f) h |= 0x8000u;
        o[c] = h;
    }
    uint2 pk;
    pk.x = (uint)o[0] | ((uint)o[1] << 16);
    pk.y = (uint)o[2] | ((uint)o[3] << 16);
    *reinterpret_cast<uint2*>(adjp + base) = pk;
}

// ---------------------------------------------------------------------------
// prep weights: Wwb[k][d][f] = bf16(Ww[k][d][f]) padded; ATb[k][d][d2] =
// bf16(A[k][d2][d]) padded (transposed for contiguous B-frag reads).
__global__ __launch_bounds__(256) void k_prepw(const float* __restrict__ Ww,
                                               const float* __restrict__ A,
                                               ushort* __restrict__ Wwb,
                                               ushort* __restrict__ ATb) {
    int k = blockIdx.y;
    int idx = blockIdx.x * 256 + threadIdx.x;     // over DP*DP = 25600
    int d = idx / DP, f = idx % DP;
    const float* Wk = Ww + (size_t)k * DD * DD;
    const float* Ak = A + (size_t)k * DD * DD;
    ushort wv = 0, av = 0;
    if (d < DD && f < DD) {
        wv = f2bf(Wk[d * DD + f]);
        av = f2bf(Ak[f * DD + d]);
    }
    Wwb[(size_t)k * DP * DP + idx] = wv;
    ATb[(size_t)k * DP * DP + idx] = av;
}

// ---------------------------------------------------------------------------
// embed: x[b,n,d] = sum_f c_hs[b,n,f] * We[d,f]; also emits x_bf (padded).
__global__ __launch_bounds__(256) void k_embed(const float* __restrict__ chs,
                                               const float* __restrict__ We,
                                               float* __restrict__ x,
                                               ushort* __restrict__ x_bf) {
    __shared__ float s_we[FIN * 144];
    __shared__ float s_in[32 * FIN];
    int bn0 = blockIdx.x * 32;
    int tid = threadIdx.x;
    for (int idx = tid; idx < DD * FIN; idx += 256) {
        int r = idx / FIN, c = idx % FIN;
        s_we[c * 144 + r] = We[idx];
    }
    for (int idx = tid; idx < 32 * FIN; idx += 256)
        s_in[idx] = chs[(size_t)bn0 * FIN + idx];
    __syncthreads();
    int d = tid;
    if (d < DD) {
        float acc[32];
#pragma unroll
        for (int r = 0; r < 32; ++r) acc[r] = 0.f;
        for (int f = 0; f < FIN; ++f) {
            float w = s_we[f * 144 + d];
#pragma unroll
            for (int r = 0; r < 32; ++r) acc[r] = fmaf(s_in[r * FIN + f], w, acc[r]);
        }
#pragma unroll
        for (int r = 0; r < 32; ++r) {
            x[(size_t)(bn0 + r) * DD + d] = acc[r];
            x_bf[(size_t)(bn0 + r) * DP + d] = f2bf(acc[r]);
        }
    } else if (d < DP) {
#pragma unroll
        for (int r = 0; r < 32; ++r) x_bf[(size_t)(bn0 + r) * DP + d] = 0;
    }
}

// ---------------------------------------------------------------------------
// wtrans via MFMA: h = x@Ww^T + Wb ; hA = h@A.  (layer 0 only)
__global__ __launch_bounds__(256) void k_wtrans(const ushort* __restrict__ x_bf,
                                                const ushort* __restrict__ Wwb,
                                                const ushort* __restrict__ ATb,
                                                const float* __restrict__ Wb,
                                                ushort* __restrict__ h_bf,
                                                ushort* __restrict__ hA_bf,
                                                ushort* __restrict__ hT_bf) {
    __shared__ __align__(16) ushort s_h[32][168];
    int bn0 = blockIdx.x * 32;
    int b = bn0 >> 9, n0 = bn0 & (NN - 1);
    int tid = threadIdx.x;
    int w = tid >> 6, l = tid & 63;
    int wm = w & 1, wc = w >> 1;
    int lr = l & 15, kg = l >> 4;
    const ushort* xrow = x_bf + (size_t)(bn0 + wm * 16 + lr) * DP;
    f32x4 acc[5];
#pragma unroll
    for (int nt = 0; nt < 5; ++nt) acc[nt] = (f32x4)(0.f);
    for (int f0 = 0; f0 < DP; f0 += 32) {
        bf16x8 a = *reinterpret_cast<const bf16x8*>(xrow + f0 + kg * 8);
#pragma unroll
        for (int nt = 0; nt < 5; ++nt) {
            int col = (wc * 5 + nt) * 16 + lr;
            bf16x8 bfr = *reinterpret_cast<const bf16x8*>(Wwb + (size_t)col * DP + f0 + kg * 8);
            acc[nt] = __builtin_amdgcn_mfma_f32_16x16x32_bf16(a, bfr, acc[nt], 0, 0, 0);
        }
    }
#pragma unroll
    for (int nt = 0; nt < 5; ++nt) {
        int col = (wc * 5 + nt) * 16 + lr;
        float bias = col < DD ? Wb[col] : 0.f;
#pragma unroll
        for (int r = 0; r < 4; ++r) {
            int rowl = wm * 16 + kg * 4 + r;
            float v = col < DD ? acc[nt][r] + bias : 0.f;
            ushort u = f2bf(v);
            s_h[rowl][col] = u;
            h_bf[(size_t)(bn0 + rowl) * DP + col] = u;
        }
        acc[nt] = (f32x4)(0.f);
    }
    __syncthreads();
    for (int f0 = 0; f0 < DP; f0 += 32) {
        bf16x8 a = *reinterpret_cast<const bf16x8*>(&s_h[wm * 16 + lr][f0 + kg * 8]);
#pragma unroll
        for (int nt = 0; nt < 5; ++nt) {
            int col = (wc * 5 + nt) * 16 + lr;
            bf16x8 bfr = *reinterpret_cast<const bf16x8*>(ATb + (size_t)col * DP + f0 + kg * 8);
            acc[nt] = __builtin_amdgcn_mfma_f32_16x16x32_bf16(a, bfr, acc[nt], 0, 0, 0);
        }
    }
#pragma unroll
    for (int nt = 0; nt < 5; ++nt) {
        int col = (wc * 5 + nt) * 16 + lr;
#pragma unroll
        for (int r = 0; r < 4; ++r)
            hA_bf[(size_t)(bn0 + wm * 16 + kg * 4 + r) * DP + col] = f2bf(acc[nt][r]);
    }
    if (tid < DP) {
        int d = tid;
        ushort tmp[32];
#pragma unroll
        for (int nn = 0; nn < 32; ++nn) tmp[nn] = s_h[nn][d];
        ushort* dst = hT_bf + ((size_t)b * DP + d) * NN + n0;
#pragma unroll
        for (int q = 0; q < 4; ++q)
            *reinterpret_cast<bf16x8*>(dst + q * 8) = *reinterpret_cast<const bf16x8*>(tmp + q * 8);
    }
}

// ---------------------------------------------------------------------------
// esym via MFMA, TRIANGLE grid (bi<=bj): e and adjp-mask are symmetric, so
// each off-diagonal tile is computed once and written twice (mirror via LDS
// transpose). Stats: direct row-sums (slot bj*2+wn) + mirror column-sums
// (slot bi*2+wm) from the SAME exp values. Diagonal blocks skip the mirror.
__global__ __launch_bounds__(256) void k_esym(const ushort* __restrict__ h_bf,
                                              const ushort* __restrict__ hA_bf,
                                              const ushort* __restrict__ adjp,
                                              ushort* __restrict__ e,
                                              float* __restrict__ Sp) {
    __shared__ ushort s_t[64 * 66];   // 8.4 KB transpose staging
    int b = blockIdx.y;
    int idx = blockIdx.x;             // 0..35 upper-triangle index
    int bi = 0;
    while (idx >= 8 - bi) { idx -= 8 - bi; ++bi; }
    int bj = bi + idx;
    int i0 = bi * 64, j0 = bj * 64;
    int w = threadIdx.x >> 6, l = threadIdx.x & 63;
    int wm = w & 1, wn = w >> 1;
    int lr = l & 15, kg = l >> 4;
    const ushort* hb = h_bf + (size_t)b * NN * DP;
    const ushort* ab = hA_bf + (size_t)b * NN * DP;
    f32x4 acc[2][2];
#pragma unroll
    for (int mt = 0; mt < 2; ++mt)
#pragma unroll
        for (int nt = 0; nt < 2; ++nt) acc[mt][nt] = (f32x4)(0.f);
    size_t moff[2], noff[2];
#pragma unroll
    for (int t = 0; t < 2; ++t) {
        moff[t] = (size_t)(i0 + wm * 32 + t * 16 + lr) * DP;
        noff[t] = (size_t)(j0 + wn * 32 + t * 16 + lr) * DP;
    }
    for (int d0 = 0; d0 < DP; d0 += 32) {
        int off = d0 + kg * 8;
        bf16x8 am[2], hm[2], hn[2], an[2];
#pragma unroll
        for (int t = 0; t < 2; ++t) {
            am[t] = *reinterpret_cast<const bf16x8*>(ab + moff[t] + off);
            hm[t] = *reinterpret_cast<const bf16x8*>(hb + moff[t] + off);
            hn[t] = *reinterpret_cast<const bf16x8*>(hb + noff[t] + off);
            an[t] = *reinterpret_cast<const bf16x8*>(ab + noff[t] + off);
        }
#pragma unroll
        for (int mt = 0; mt < 2; ++mt)
#pragma unroll
            for (int nt = 0; nt < 2; ++nt) {
                acc[mt][nt] = __builtin_amdgcn_mfma_f32_16x16x32_bf16(am[mt], hn[nt], acc[mt][nt], 0, 0, 0);
                acc[mt][nt] = __builtin_amdgcn_mfma_f32_16x16x32_bf16(hm[mt], an[nt], acc[mt][nt], 0, 0, 0);
            }
    }
    ushort* eb = e + (size_t)b * NN * NN;
    ushort eh[2][2][4];
#pragma unroll
    for (int mt = 0; mt < 2; ++mt) {
        int rbase = i0 + wm * 32 + mt * 16 + kg * 4;
#pragma unroll
        for (int nt = 0; nt < 2; ++nt) {
            int col = j0 + wn * 32 + nt * 16 + lr;
#pragma unroll
            for (int r = 0; r < 4; ++r) {
                ushort u = f2h_bits(acc[mt][nt][r]);
                eh[mt][nt][r] = u;
                eb[(size_t)(rbase + r) * NN + col] = u;
            }
        }
    }
    // exp values + masks (once; reused by both stat directions)
    const ushort* ap = adjp + (size_t)b * NN * NN + (size_t)i0 * NN + j0;
    float ev[2][2][4];
    bool mk[2][2][4];
#pragma unroll
    for (int mt = 0; mt < 2; ++mt)
#pragma unroll
        for (int nt = 0; nt < 2; ++nt) {
            int coll = wn * 32 + nt * 16 + lr;
#pragma unroll
            for (int r = 0; r < 4; ++r) {
                int rowl = wm * 32 + mt * 16 + kg * 4 + r;
                ev[mt][nt][r] = __expf(acc[mt][nt][r]);
                mk[mt][nt][r] = (ap[(size_t)rowl * NN + coll] & 0x8000u) != 0;
            }
        }
    // direct stats: row sums over this wave's 32-col slice -> slot bj*2+wn
    {
        int slot = bj * 2 + wn;
        float* Sp1 = Sp + (((size_t)b) * 16 + slot) * NN;
        float* Sp2 = Sp + (((size_t)BB + b) * 16 + slot) * NN;
#pragma unroll
        for (int mt = 0; mt < 2; ++mt) {
#pragma unroll
            for (int r = 0; r < 4; ++r) {
                float v1 = 0.f, v2 = 0.f;
#pragma unroll
                for (int nt = 0; nt < 2; ++nt) {
                    v2 += ev[mt][nt][r];
                    if (mk[mt][nt][r]) v1 += ev[mt][nt][r];
                }
#pragma unroll
                for (int off = 1; off < 16; off <<= 1) {
                    v1 += __shfl_xor(v1, off);
                    v2 += __shfl_xor(v2, off);
                }
                if (lr == 0) {
                    int rowl = wm * 32 + mt * 16 + kg * 4 + r;
                    Sp1[i0 + rowl] = v1;
                    Sp2[i0 + rowl] = v2;
                }
            }
        }
    }
    if (bi != bj) {
        // mirror stats: column sums (rows J, cols I wm-half) -> slot bi*2+wm
        int slot = bi * 2 + wm;
        float* Sp1 = Sp + (((size_t)b) * 16 + slot) * NN;
        float* Sp2 = Sp + (((size_t)BB + b) * 16 + slot) * NN;
#pragma unroll
        for (int nt = 0; nt < 2; ++nt) {
            float v1 = 0.f, v2 = 0.f;
#pragma unroll
            for (int mt = 0; mt < 2; ++mt)
#pragma unroll
                for (int r = 0; r < 4; ++r) {
                    v2 += ev[mt][nt][r];
                    if (mk[mt][nt][r]) v1 += ev[mt][nt][r];
                }
            v1 += __shfl_xor(v1, 16); v2 += __shfl_xor(v2, 16);
            v1 += __shfl_xor(v1, 32); v2 += __shfl_xor(v2, 32);
            if (kg == 0) {
                int rowm = j0 + wn * 32 + nt * 16 + lr;
                Sp1[rowm] = v1;
                Sp2[rowm] = v2;
            }
        }
        // mirror e-tile via LDS transpose
#pragma unroll
        for (int mt = 0; mt < 2; ++mt) {
#pragma unroll
            for (int nt = 0; nt < 2; ++nt) {
                int coll = wn * 32 + nt * 16 + lr;
#pragma unroll
                for (int r = 0; r < 4; ++r) {
                    int rowl = wm * 32 + mt * 16 + kg * 4 + r;
                    s_t[rowl * 66 + coll] = eh[mt][nt][r];
                }
            }
        }
        __syncthreads();
        int a = threadIdx.x >> 2, c0 = (threadIdx.x & 3) * 16;   // mirror row, col-seg
        ushort tmp[16];
#pragma unroll
        for (int q = 0; q < 16; ++q) tmp[q] = s_t[(c0 + q) * 66 + a];
        ushort* dst = eb + (size_t)(j0 + a) * NN + i0 + c0;
        *reinterpret_cast<bf16x8*>(dst) = *reinterpret_cast<const bf16x8*>(tmp);
        *reinterpret_cast<bf16x8*>(dst + 8) = *reinterpret_cast<const bf16x8*>(tmp + 8);
    }
}

// ---------------------------------------------------------------------------
// sred: reduce Sp 16-slot partials to reciprocal denominators ONCE.
__global__ __launch_bounds__(256) void k_sred(const float* __restrict__ Sp,
                                              float* __restrict__ Cr) {
    int b = blockIdx.y;
    int j = blockIdx.x * 256 + threadIdx.x;
    const float* Sp1 = Sp + ((size_t)b) * 16 * NN;
    const float* Sp2 = Sp + ((size_t)(BB + b)) * 16 * NN;
    float a1 = 0.f, a2 = 0.f;
#pragma unroll
    for (int jb = 0; jb < 16; ++jb) {
        a1 += Sp1[jb * NN + j];
        a2 += Sp2[jb * NN + j];
    }
    Cr[(size_t)b * NN + j] = 1.0f / a1;
    Cr[(size_t)(BB + b) * NN + j] = 1.0f / a2;
}

// ---------------------------------------------------------------------------
// hprime + gate + NEXT-LAYER wtrans, fused. 16 i-rows per block, 256 threads
// (R13 structure: 4 waves = path x col-half). Denominators from Cr.
__global__ __launch_bounds__(256) void k_hprime(const ushort* __restrict__ e,
                                                const ushort* __restrict__ adjp,
                                                const ushort* __restrict__ hT_bf,
                                                const float* __restrict__ Cr,
                                                const float* __restrict__ gw,
                                                const float* __restrict__ gb,
                                                float* __restrict__ x,
                                                const ushort* __restrict__ Wwb2,
                                                const ushort* __restrict__ ATb2,
                                                const float* __restrict__ Wb2,
                                                int do_next,
                                                ushort* __restrict__ h2_bf,
                                                ushort* __restrict__ hA2_bf,
                                                ushort* __restrict__ hT2_bf) {
    __shared__ ushort s_att[2][2][4][16 * 40]; // [buf][path][sub][row*40+j] 20 KB
    __shared__ float s_C[2][NN];               // 4 KB (reciprocal denominators)
    __shared__ float s_h2[16][RST];            // 9.25 KB (path-1 hp tile)
    __shared__ float s_pz[4][16];
    __shared__ float s_px[2][16];
    // epilogue aliases (s_att dead after main loop): 2 x 16*168 ushorts = 10.5KB
    ushort* s_x  = &s_att[0][0][0][0];
    ushort* s_hh = s_x + 16 * 168;
    int b = blockIdx.y, i0 = blockIdx.x * 16;
    int tid = threadIdx.x;
    int w = tid >> 6, l = tid & 63;
    int p = w >> 1, half = w & 1;
    int ntb = half * 5, ncnt = half ? 4 : 5;
    int lr = l & 15, kg = l >> 4;
    int ai = tid >> 4, aj8 = (tid & 15) * 8;   // row, j-offset within 128-chunk
    int sub = aj8 >> 5, jj = aj8 & 31;
    const ushort* e_row = e + (size_t)b * NN * NN + (size_t)(i0 + ai) * NN;
    const ushort* p_row = adjp + (size_t)b * NN * NN + (size_t)(i0 + ai) * NN;
    const ushort* hTb = hT_bf + (size_t)b * DP * NN;

    // ---- issue ALL global loads up front (4 chunks x (e,adjp)) ----
    uint4 e_r[4], p_r[4];
#pragma unroll
    for (int c = 0; c < 4; ++c) {
        e_r[c] = *reinterpret_cast<const uint4*>(e_row + c * 128 + aj8);
        p_r[c] = *reinterpret_cast<const uint4*>(p_row + c * 128 + aj8);
    }
    float xq[5][4];
    if (p == 0) {
#pragma unroll
        for (int nt = 0; nt < 5; ++nt) {
            int col = (ntb + nt) * 16 + lr;
            bool ok = (nt < ncnt) && (col < DD);
#pragma unroll
            for (int r = 0; r < 4; ++r) {
                int row = kg * 4 + r;
                xq[nt][r] = ok ? x[((size_t)b * NN + i0 + row) * DD + col] : 0.f;
            }
        }
    }
    // stage reciprocal denominators (pre-reduced by k_sred)
    for (int idx = tid; idx < NN; idx += 256) {
        s_C[0][idx] = Cr[(size_t)b * NN + idx];
        s_C[1][idx] = Cr[(size_t)(BB + b) * NN + idx];
    }

    auto build = [&](const uint4& ev4, const uint4& pv4, int cbase, int buf) {
        uint ew[4] = {ev4.x, ev4.y, ev4.z, ev4.w};
        uint pw[4] = {pv4.x, pv4.y, pv4.z, pv4.w};
        ushort o1[8], o2[8];
#pragma unroll
        for (int q = 0; q < 4; ++q) {
            float ev[2] = {h2f_bits((ushort)(ew[q] & 0xFFFFu)), h2f_bits((ushort)(ew[q] >> 16))};
            ushort hb[2] = {(ushort)(pw[q] & 0xFFFFu), (ushort)(pw[q] >> 16)};
#pragma unroll
            for (int c2 = 0; c2 < 2; ++c2) {
                int idx = q * 2 + c2;
                int jg = cbase + aj8 + idx;
                bool mask = (hb[c2] & 0x8000u) != 0;
                float a2 = h2f_bits((ushort)(hb[c2] & 0x7FFFu));
                float eexp = __expf(ev[c2]);
                float att1 = eexp * s_C[0][jg];
                float att2 = a2 * eexp * s_C[1][jg];
                o1[idx] = mask ? f2bf(att1) : (ushort)0;
                o2[idx] = f2bf(att2);
            }
        }
        uint4 w1, w2;
        w1.x = (uint)o1[0] | ((uint)o1[1] << 16); w1.y = (uint)o1[2] | ((uint)o1[3] << 16);
        w1.z = (uint)o1[4] | ((uint)o1[5] << 16); w1.w = (uint)o1[6] | ((uint)o1[7] << 16);
        w2.x = (uint)o2[0] | ((uint)o2[1] << 16); w2.y = (uint)o2[2] | ((uint)o2[3] << 16);
        w2.z = (uint)o2[4] | ((uint)o2[5] << 16); w2.w = (uint)o2[6] | ((uint)o2[7] << 16);
        *reinterpret_cast<uint4*>(&s_att[buf][0][sub][ai * 40 + jj]) = w1;
        *reinterpret_cast<uint4*>(&s_att[buf][1][sub][ai * 40 + jj]) = w2;
    };

    f32x4 acc[5];
#pragma unroll
    for (int nt = 0; nt < 5; ++nt) acc[nt] = (f32x4)(0.f);

    __syncthreads();           // s_C ready
    build(e_r[0], p_r[0], 0, 0);
    __syncthreads();
#pragma unroll
    for (int c = 0; c < 4; ++c) {
        int cb = c & 1, nb = cb ^ 1;
        if (c < 3) build(e_r[c + 1], p_r[c + 1], (c + 1) * 128, nb);
#pragma unroll
        for (int s4 = 0; s4 < 4; ++s4) {
            int j0 = c * 128 + s4 * 32;
            bf16x8 afr = *reinterpret_cast<const bf16x8*>(&s_att[cb][p][s4][lr * 40 + kg * 8]);
#pragma unroll
            for (int nt = 0; nt < 5; ++nt) {
                if (nt < ncnt) {
                    bf16x8 bfr = *reinterpret_cast<const bf16x8*>(
                        hTb + (size_t)((ntb + nt) * 16 + lr) * NN + j0 + kg * 8);
                    acc[nt] = __builtin_amdgcn_mfma_f32_16x16x32_bf16(afr, bfr, acc[nt], 0, 0, 0);
                }
            }
        }
        __syncthreads();
    }
    // relu + gate partials (wave-local complete j-sums)
    float z4[4] = {0.f, 0.f, 0.f, 0.f}, sx4[4] = {0.f, 0.f, 0.f, 0.f};
#pragma unroll
    for (int nt = 0; nt < 5; ++nt) {
        if (nt < ncnt) {
            int col = (ntb + nt) * 16 + lr;
            bool ok = col < DD;
            float g1 = ok ? gw[DD + col] : 0.f;
            float g0 = (ok && p == 0) ? gw[col] : 0.f;
#pragma unroll
            for (int r = 0; r < 4; ++r) {
                float hp = fmaxf(acc[nt][r], 0.f);
                acc[nt][r] = hp;
                z4[r] = fmaf(g1, hp, z4[r]);
                if (p == 0) sx4[r] = fmaf(g0, xq[nt][r], sx4[r]);
            }
        }
    }
#pragma unroll
    for (int off = 1; off < 16; off <<= 1) {
#pragma unroll
        for (int r = 0; r < 4; ++r) {
            z4[r] += __shfl_xor(z4[r], off);
            if (p == 0) sx4[r] += __shfl_xor(sx4[r], off);
        }
    }
    if (lr == 0) {
#pragma unroll
        for (int r = 0; r < 4; ++r) {
            s_pz[w][kg * 4 + r] = z4[r];
            if (p == 0) s_px[w][kg * 4 + r] = sx4[r];
        }
    }
    if (p == 1) {
#pragma unroll
        for (int nt = 0; nt < 5; ++nt) {
            if (nt < ncnt) {
                int col = (ntb + nt) * 16 + lr;
#pragma unroll
                for (int r = 0; r < 4; ++r)
                    s_h2[kg * 4 + r][col] = acc[nt][r];
            }
        }
    }
    __syncthreads();
    if (p == 0) {
        float gbv = gb[0];
#pragma unroll
        for (int r = 0; r < 4; ++r) {
            int row = kg * 4 + r;
            float sx = s_px[0][row] + s_px[1][row];
            float z1 = s_pz[0][row] + s_pz[1][row];
            float z2 = s_pz[2][row] + s_pz[3][row];
            float c1 = 1.f / (1.f + __expf(-(sx + z1 + gbv)));
            float c2 = 1.f / (1.f + __expf(-(sx + z2 + gbv)));
#pragma unroll
            for (int nt = 0; nt < 5; ++nt) {
                if (nt < ncnt) {
                    int col = (ntb + nt) * 16 + lr;
                    if (col < DD) {
                        float xnew = (c2 - c1) * xq[nt][r] + (1.f - c2) * s_h2[row][col]
                                   - (1.f - c1) * acc[nt][r];
                        size_t bn = (size_t)b * NN + i0 + row;
                        x[bn * DD + col] = xnew;
                        s_x[row * 168 + col] = f2bf(xnew);
                    }
                }
            }
        }
    } else if (do_next) {
        // zero-fill s_x pad cols 140..159 (16 rows x 20 cols = 320)
        for (int idx = tid - 128; idx < 320; idx += 128) {
            int row = idx / 20, col = DD + idx % 20;
            s_x[row * 168 + col] = 0;
        }
    }
    if (do_next) {
        __syncthreads();       // s_x complete
        int ntile = (w < 2) ? 3 : 2;
        f32x4 acc2[3];
#pragma unroll
        for (int q = 0; q < 3; ++q) acc2[q] = (f32x4)(0.f);
        // GEMM1: h = xnew @ Ww2^T (+Wb2)
        for (int f0 = 0; f0 < DP; f0 += 32) {
            bf16x8 a = *reinterpret_cast<const bf16x8*>(&s_x[lr * 168 + f0 + kg * 8]);
#pragma unroll
            for (int q = 0; q < 3; ++q) {
                if (q < ntile) {
                    int col = (w + q * 4) * 16 + lr;
                    bf16x8 bfr = *reinterpret_cast<const bf16x8*>(Wwb2 + (size_t)col * DP + f0 + kg * 8);
                    acc2[q] = __builtin_amdgcn_mfma_f32_16x16x32_bf16(a, bfr, acc2[q], 0, 0, 0);
                }
            }
        }
#pragma unroll
        for (int q = 0; q < 3; ++q) {
            if (q < ntile) {
                int col = (w + q * 4) * 16 + lr;
                float bias = col < DD ? Wb2[col] : 0.f;
#pragma unroll
                for (int r = 0; r < 4; ++r) {
                    int row = kg * 4 + r;
                    float v = col < DD ? acc2[q][r] + bias : 0.f;
                    ushort u = f2bf(v);
                    s_hh[row * 168 + col] = u;
                    h2_bf[((size_t)b * NN + i0 + row) * DP + col] = u;
                }
                acc2[q] = (f32x4)(0.f);
            }
        }
        __syncthreads();       // s_hh complete
        // GEMM2: hA = h @ A2
        for (int f0 = 0; f0 < DP; f0 += 32) {
            bf16x8 a = *reinterpret_cast<const bf16x8*>(&s_hh[lr * 168 + f0 + kg * 8]);
#pragma unroll
            for (int q = 0; q < 3; ++q) {
                if (q < ntile) {
                    int col = (w + q * 4) * 16 + lr;
                    bf16x8 bfr = *reinterpret_cast<const bf16x8*>(ATb2 + (size_t)col * DP + f0 + kg * 8);
                    acc2[q] = __builtin_amdgcn_mfma_f32_16x16x32_bf16(a, bfr, acc2[q], 0, 0, 0);
                }
            }
        }
#pragma unroll
        for (int q = 0; q < 3; ++q) {
            if (q < ntile) {
                int col = (w + q * 4) * 16 + lr;
#pragma unroll
                for (int r = 0; r < 4; ++r)
                    hA2_bf[((size_t)b * NN + i0 + kg * 4 + r) * DP + col] = f2bf(acc2[q][r]);
            }
        }
        // hT for next layer (16 columns i0..i0+16)
        if (tid < DP) {
            int d = tid;
            ushort tmp[16];
#pragma unroll
            for (int nn = 0; nn < 16; ++nn) tmp[nn] = s_hh[nn * 168 + d];
            ushort* dst = hT2_bf + ((size_t)b * DP + d) * NN + i0;
            *reinterpret_cast<bf16x8*>(dst) = *reinterpret_cast<const bf16x8*>(tmp);
            *reinterpret_cast<bf16x8*>(dst + 8) = *reinterpret_cast<const bf16x8*>(tmp + 8);
        }
    }
}

// ---------------------------------------------------------------------------
// readout: g[b,d] = sum_n x[b,n,d] * valid[b,n]
__global__ __launch_bounds__(256) void k_readout(const float* __restrict__ x,
                                                 const float* __restrict__ valid,
                                                 float* __restrict__ g) {
    int b = blockIdx.x;
    int t = threadIdx.x;
    if (t < DD) {
        float acc = 0.f;
        for (int n = 0; n < NN; ++n)
            acc = fmaf(x[((size_t)b * NN + n) * DD + t], valid[b * NN + n], acc);
        g[b * DD + t] = acc;
    }
}

// ---------------------------------------------------------------------------
// tiny MLP head: relu x3 + sigmoid
__global__ __launch_bounds__(128) void k_mlp(const float* __restrict__ g,
                                             const float* __restrict__ w0, const float* __restrict__ b0,
                                             const float* __restrict__ w1, const float* __restrict__ b1,
                                             const float* __restrict__ w2, const float* __restrict__ b2,
                                             const float* __restrict__ w3, const float* __restrict__ b3,
                                             float* __restrict__ out) {
    __shared__ float s0[DD];
    __shared__ float s1[DF];
    __shared__ float s2[DF];
    __shared__ float s_part[2];
    int b = blockIdx.x, t = threadIdx.x;
    for (int i = t; i < DD; i += 128) s0[i] = g[b * DD + i];
    __syncthreads();
    float acc = b0[t];
    for (int dd2 = 0; dd2 < DD; ++dd2) acc = fmaf(s0[dd2], w0[dd2 * DF + t], acc);
    s1[t] = fmaxf(acc, 0.f);
    __syncthreads();
    acc = b1[t];
    for (int dd2 = 0; dd2 < DF; ++dd2) acc = fmaf(s1[dd2], w1[dd2 * DF + t], acc);
    s2[t] = fmaxf(acc, 0.f);
    __syncthreads();
    acc = b2[t];
    for (int dd2 = 0; dd2 < DF; ++dd2) acc = fmaf(s2[dd2], w2[dd2 * DF + t], acc);
    float h3 = fmaxf(acc, 0.f);
    float p = h3 * w3[t];
#pragma unroll
    for (int off = 32; off > 0; off >>= 1) p += __shfl_down(p, off);
    if ((t & 63) == 0) s_part[t >> 6] = p;
    __syncthreads();
    if (t == 0) {
        float s = s_part[0] + s_part[1] + b3[0];
        out[b] = 1.f / (1.f + __expf(-s));
    }
}

// ---------------------------------------------------------------------------
extern "C" void kernel_launch(void* const* d_in, const int* in_sizes, int n_in,
                              void* d_out, int out_size, void* d_ws, size_t ws_size,
                              hipStream_t stream) {
    const float* chs   = (const float*)d_in[0];
    const float* adj1  = (const float*)d_in[1];
    const float* dist  = (const float*)d_in[2];
    const float* valid = (const float*)d_in[3];
    const float* We    = (const float*)d_in[4];
    const float* Ww    = (const float*)d_in[5];
    const float* Wb    = (const float*)d_in[6];
    const float* A     = (const float*)d_in[7];
    const float* gw    = (const float*)d_in[8];
    const float* gb    = (const float*)d_in[9];
    const float* mu    = (const float*)d_in[10];
    const float* dev   = (const float*)d_in[11];
    const float* w0    = (const float*)d_in[12];
    const float* b0    = (const float*)d_in[13];
    const float* w1    = (const float*)d_in[14];
    const float* b1    = (const float*)d_in[15];
    const float* w2    = (const float*)d_in[16];
    const float* b2    = (const float*)d_in[17];
    const float* w3    = (const float*)d_in[18];
    const float* b3    = (const float*)d_in[19];
    float* out = (float*)d_out;

    const size_t SX  = (size_t)BB * NN * DD;
    const size_t SNN = (size_t)BB * NN * NN;
    const size_t SBF = (size_t)BB * NN * DP;
    const size_t SSP = (size_t)2 * BB * 16 * NN;   // stats partials
    float* ws  = (float*)d_ws;
    float* x   = ws;
    float* Sp  = x + SX;
    float* Cr  = Sp + SSP;                         // 2*BB*NN reciprocals
    float* g   = Cr + (size_t)2 * BB * NN;
    ushort* hset0  = (ushort*)(g + BB * DD);      // h, hA, hT (set 0)
    ushort* hset1  = hset0 + 3 * SBF;             // h, hA, hT (set 1)
    ushort* x_bf   = hset1 + 3 * SBF;
    ushort* Wwb    = x_bf + SBF;
    ushort* ATb    = Wwb + (size_t)LL * DP * DP;
    ushort* adjp   = ATb + (size_t)LL * DP * DP;  // BB*NN*NN fp16 (signed)
    ushort* e_h    = adjp + SNN;                  // BB*NN*NN fp16

    k_prepa<<<SNN / 1024, 256, 0, stream>>>(adj1, dist, mu, dev, adjp);
    k_prepw<<<dim3(DP * DP / 256, LL), 256, 0, stream>>>(Ww, A, Wwb, ATb);
    k_embed<<<BB * NN / 32, 256, 0, stream>>>(chs, We, x, x_bf);

    // layer-0 transforms
    k_wtrans<<<BB * NN / 32, 256, 0, stream>>>(x_bf, Wwb, ATb, Wb,
                                               hset0, hset0 + SBF, hset0 + 2 * SBF);

    for (int k = 0; k < LL; ++k) {
        ushort* cur = (k & 1) ? hset1 : hset0;
        ushort* nxt = (k & 1) ? hset0 : hset1;
        int kn = (k < LL - 1) ? k + 1 : k;
        const float* gwk = gw + (size_t)k * 2 * DD;
        const float* gbk = gb + k;
        k_esym<<<dim3(36, BB), 256, 0, stream>>>(cur, cur + SBF, adjp, e_h, Sp);
        k_sred<<<dim3(NN / 256, BB), 256, 0, stream>>>(Sp, Cr);
        k_hprime<<<dim3(NN / 16, BB), 256, 0, stream>>>(
            e_h, adjp, cur + 2 * SBF, Cr, gwk, gbk, x,
            Wwb + (size_t)kn * DP * DP, ATb + (size_t)kn * DP * DP, Wb + (size_t)kn * DD,
            (k < LL - 1) ? 1 : 0,
            nxt, nxt + SBF, nxt + 2 * SBF);
    }

    k_readout<<<BB, 256, 0, stream>>>(x, valid, g);
    k_mlp<<<BB, 128, 0, stream>>>(g, w0, b0, w1, b1, w2, b2, w3, b3, out);
}

// Round 17
// 381.425 us; speedup vs baseline: 1.1091x; 1.0849x over previous
//
#include <hip/hip_runtime.h>
#include <hip/hip_fp16.h>

#define BB 32
#define NN 512
#define FIN 74
#define DD 140
#define DP 160            // padded d (zero-filled 140..159), multiple of 32
#define DF 128
#define LL 4
#define NEGV (-9e15f)
#define RST 148           // s_h2 stride (floats)

typedef __attribute__((ext_vector_type(8))) short bf16x8;
typedef __attribute__((ext_vector_type(4))) float f32x4;

__device__ inline ushort f2bf(float x) {
    union { float f; unsigned u; } v; v.f = x;
    unsigned r = (v.u + 0x7FFFu + ((v.u >> 16) & 1u)) >> 16;   // RNE
    return (ushort)r;
}
__device__ inline ushort f2h_bits(float x) {
    __half h = __float2half(x);
    union { __half h; ushort u; } c; c.h = h; return c.u;
}
__device__ inline float h2f_bits(ushort u) {
    union { __half h; ushort u; } c; c.u = u; return __half2float(c.h);
}

// ---------------------------------------------------------------------------
// prep adjacency: adjp[b,i,j] = fp16(exp(-(dist-mu)^2/dev) + a1), sign bit =
// (a1>0). a1 is exactly 0/1; exp term >= e^-16 ~ 1.1e-7 > fp16 min subnormal.
__global__ __launch_bounds__(256) void k_prepa(const float* __restrict__ adj1,
                                               const float* __restrict__ dist,
                                               const float* __restrict__ mu_p,
                                               const float* __restrict__ dev_p,
                                               ushort* __restrict__ adjp) {
    float mu = mu_p[0], rdev = 1.0f / dev_p[0];
    size_t base = ((size_t)blockIdx.x * 256 + threadIdx.x) * 4;
    float4 av = *reinterpret_cast<const float4*>(adj1 + base);
    float4 dv = *reinterpret_cast<const float4*>(dist + base);
    float aa[4] = {av.x, av.y, av.z, av.w};
    float dd[4] = {dv.x, dv.y, dv.z, dv.w};
    ushort o[4];
#pragma unroll
    for (int c = 0; c < 4; ++c) {
        float t = dd[c] - mu;
        float a2 = __expf(-t * t * rdev) + aa[c];
        ushort h = f2h_bits(a2);
        if (aa[c] > 0.f) h |= 0x8000u;
        o[c] = h;
    }
    uint2 pk;
    pk.x = (uint)o[0] | ((uint)o[1] << 16);
    pk.y = (uint)o[2] | ((uint)o[3] << 16);
    *reinterpret_cast<uint2*>(adjp + base) = pk;
}

// ---------------------------------------------------------------------------
// prep weights: Wwb[k][d][f] = bf16(Ww[k][d][f]) padded; ATb[k][d][d2] =
// bf16(A[k][d2][d]) padded (transposed for contiguous B-frag reads).
__global__ __launch_bounds__(256) void k_prepw(const float* __restrict__ Ww,
                                               const float* __restrict__ A,
                                               ushort* __restrict__ Wwb,
                                               ushort* __restrict__ ATb) {
    int k = blockIdx.y;
    int idx = blockIdx.x * 256 + threadIdx.x;     // over DP*DP = 25600
    int d = idx / DP, f = idx % DP;
    const float* Wk = Ww + (size_t)k * DD * DD;
    const float* Ak = A + (size_t)k * DD * DD;
    ushort wv = 0, av = 0;
    if (d < DD && f < DD) {
        wv = f2bf(Wk[d * DD + f]);
        av = f2bf(Ak[f * DD + d]);
    }
    Wwb[(size_t)k * DP * DP + idx] = wv;
    ATb[(size_t)k * DP * DP + idx] = av;
}

// ---------------------------------------------------------------------------
// embed: x[b,n,d] = sum_f c_hs[b,n,f] * We[d,f]; also emits x_bf (padded).
__global__ __launch_bounds__(256) void k_embed(const float* __restrict__ chs,
                                               const float* __restrict__ We,
                                               float* __restrict__ x,
                                               ushort* __restrict__ x_bf) {
    __shared__ float s_we[FIN * 144];
    __shared__ float s_in[32 * FIN];
    int bn0 = blockIdx.x * 32;
    int tid = threadIdx.x;
    for (int idx = tid; idx < DD * FIN; idx += 256) {
        int r = idx / FIN, c = idx % FIN;
        s_we[c * 144 + r] = We[idx];
    }
    for (int idx = tid; idx < 32 * FIN; idx += 256)
        s_in[idx] = chs[(size_t)bn0 * FIN + idx];
    __syncthreads();
    int d = tid;
    if (d < DD) {
        float acc[32];
#pragma unroll
        for (int r = 0; r < 32; ++r) acc[r] = 0.f;
        for (int f = 0; f < FIN; ++f) {
            float w = s_we[f * 144 + d];
#pragma unroll
            for (int r = 0; r < 32; ++r) acc[r] = fmaf(s_in[r * FIN + f], w, acc[r]);
        }
#pragma unroll
        for (int r = 0; r < 32; ++r) {
            x[(size_t)(bn0 + r) * DD + d] = acc[r];
            x_bf[(size_t)(bn0 + r) * DP + d] = f2bf(acc[r]);
        }
    } else if (d < DP) {
#pragma unroll
        for (int r = 0; r < 32; ++r) x_bf[(size_t)(bn0 + r) * DP + d] = 0;
    }
}

// ---------------------------------------------------------------------------
// wtrans via MFMA: h = x@Ww^T + Wb ; hA = h@A.  (layer 0 only)
__global__ __launch_bounds__(256) void k_wtrans(const ushort* __restrict__ x_bf,
                                                const ushort* __restrict__ Wwb,
                                                const ushort* __restrict__ ATb,
                                                const float* __restrict__ Wb,
                                                ushort* __restrict__ h_bf,
                                                ushort* __restrict__ hA_bf,
                                                ushort* __restrict__ hT_bf) {
    __shared__ __align__(16) ushort s_h[32][168];
    int bn0 = blockIdx.x * 32;
    int b = bn0 >> 9, n0 = bn0 & (NN - 1);
    int tid = threadIdx.x;
    int w = tid >> 6, l = tid & 63;
    int wm = w & 1, wc = w >> 1;
    int lr = l & 15, kg = l >> 4;
    const ushort* xrow = x_bf + (size_t)(bn0 + wm * 16 + lr) * DP;
    f32x4 acc[5];
#pragma unroll
    for (int nt = 0; nt < 5; ++nt) acc[nt] = (f32x4)(0.f);
    for (int f0 = 0; f0 < DP; f0 += 32) {
        bf16x8 a = *reinterpret_cast<const bf16x8*>(xrow + f0 + kg * 8);
#pragma unroll
        for (int nt = 0; nt < 5; ++nt) {
            int col = (wc * 5 + nt) * 16 + lr;
            bf16x8 bfr = *reinterpret_cast<const bf16x8*>(Wwb + (size_t)col * DP + f0 + kg * 8);
            acc[nt] = __builtin_amdgcn_mfma_f32_16x16x32_bf16(a, bfr, acc[nt], 0, 0, 0);
        }
    }
#pragma unroll
    for (int nt = 0; nt < 5; ++nt) {
        int col = (wc * 5 + nt) * 16 + lr;
        float bias = col < DD ? Wb[col] : 0.f;
#pragma unroll
        for (int r = 0; r < 4; ++r) {
            int rowl = wm * 16 + kg * 4 + r;
            float v = col < DD ? acc[nt][r] + bias : 0.f;
            ushort u = f2bf(v);
            s_h[rowl][col] = u;
            h_bf[(size_t)(bn0 + rowl) * DP + col] = u;
        }
        acc[nt] = (f32x4)(0.f);
    }
    __syncthreads();
    for (int f0 = 0; f0 < DP; f0 += 32) {
        bf16x8 a = *reinterpret_cast<const bf16x8*>(&s_h[wm * 16 + lr][f0 + kg * 8]);
#pragma unroll
        for (int nt = 0; nt < 5; ++nt) {
            int col = (wc * 5 + nt) * 16 + lr;
            bf16x8 bfr = *reinterpret_cast<const bf16x8*>(ATb + (size_t)col * DP + f0 + kg * 8);
            acc[nt] = __builtin_amdgcn_mfma_f32_16x16x32_bf16(a, bfr, acc[nt], 0, 0, 0);
        }
    }
#pragma unroll
    for (int nt = 0; nt < 5; ++nt) {
        int col = (wc * 5 + nt) * 16 + lr;
#pragma unroll
        for (int r = 0; r < 4; ++r)
            hA_bf[(size_t)(bn0 + wm * 16 + kg * 4 + r) * DP + col] = f2bf(acc[nt][r]);
    }
    if (tid < DP) {
        int d = tid;
        ushort tmp[32];
#pragma unroll
        for (int nn = 0; nn < 32; ++nn) tmp[nn] = s_h[nn][d];
        ushort* dst = hT_bf + ((size_t)b * DP + d) * NN + n0;
#pragma unroll
        for (int q = 0; q < 4; ++q)
            *reinterpret_cast<bf16x8*>(dst + q * 8) = *reinterpret_cast<const bf16x8*>(tmp + q * 8);
    }
}

// ---------------------------------------------------------------------------
// esym via MFMA, TRIANGLE grid (bi<=bj): e and adjp-mask are symmetric, so
// each off-diagonal tile is computed once and written twice (mirror via LDS
// transpose). Stats: direct row-sums (slot bj*2+wn) + mirror column-sums
// (slot bi*2+wm) from the SAME exp values. Diagonal blocks skip the mirror.
__global__ __launch_bounds__(256) void k_esym(const ushort* __restrict__ h_bf,
                                              const ushort* __restrict__ hA_bf,
                                              const ushort* __restrict__ adjp,
                                              ushort* __restrict__ e,
                                              float* __restrict__ Sp) {
    __shared__ ushort s_t[64 * 66];   // 8.4 KB transpose staging
    int b = blockIdx.y;
    int idx = blockIdx.x;             // 0..35 upper-triangle index
    int bi = 0;
    while (idx >= 8 - bi) { idx -= 8 - bi; ++bi; }
    int bj = bi + idx;
    int i0 = bi * 64, j0 = bj * 64;
    int w = threadIdx.x >> 6, l = threadIdx.x & 63;
    int wm = w & 1, wn = w >> 1;
    int lr = l & 15, kg = l >> 4;
    const ushort* hb = h_bf + (size_t)b * NN * DP;
    const ushort* ab = hA_bf + (size_t)b * NN * DP;
    f32x4 acc[2][2];
#pragma unroll
    for (int mt = 0; mt < 2; ++mt)
#pragma unroll
        for (int nt = 0; nt < 2; ++nt) acc[mt][nt] = (f32x4)(0.f);
    size_t moff[2], noff[2];
#pragma unroll
    for (int t = 0; t < 2; ++t) {
        moff[t] = (size_t)(i0 + wm * 32 + t * 16 + lr) * DP;
        noff[t] = (size_t)(j0 + wn * 32 + t * 16 + lr) * DP;
    }
    for (int d0 = 0; d0 < DP; d0 += 32) {
        int off = d0 + kg * 8;
        bf16x8 am[2], hm[2], hn[2], an[2];
#pragma unroll
        for (int t = 0; t < 2; ++t) {
            am[t] = *reinterpret_cast<const bf16x8*>(ab + moff[t] + off);
            hm[t] = *reinterpret_cast<const bf16x8*>(hb + moff[t] + off);
            hn[t] = *reinterpret_cast<const bf16x8*>(hb + noff[t] + off);
            an[t] = *reinterpret_cast<const bf16x8*>(ab + noff[t] + off);
        }
#pragma unroll
        for (int mt = 0; mt < 2; ++mt)
#pragma unroll
            for (int nt = 0; nt < 2; ++nt) {
                acc[mt][nt] = __builtin_amdgcn_mfma_f32_16x16x32_bf16(am[mt], hn[nt], acc[mt][nt], 0, 0, 0);
                acc[mt][nt] = __builtin_amdgcn_mfma_f32_16x16x32_bf16(hm[mt], an[nt], acc[mt][nt], 0, 0, 0);
            }
    }
    ushort* eb = e + (size_t)b * NN * NN;
    ushort eh[2][2][4];
#pragma unroll
    for (int mt = 0; mt < 2; ++mt) {
        int rbase = i0 + wm * 32 + mt * 16 + kg * 4;
#pragma unroll
        for (int nt = 0; nt < 2; ++nt) {
            int col = j0 + wn * 32 + nt * 16 + lr;
#pragma unroll
            for (int r = 0; r < 4; ++r) {
                ushort u = f2h_bits(acc[mt][nt][r]);
                eh[mt][nt][r] = u;
                eb[(size_t)(rbase + r) * NN + col] = u;
            }
        }
    }
    // exp values + masks (once; reused by both stat directions)
    const ushort* ap = adjp + (size_t)b * NN * NN + (size_t)i0 * NN + j0;
    float ev[2][2][4];
    bool mk[2][2][4];
#pragma unroll
    for (int mt = 0; mt < 2; ++mt)
#pragma unroll
        for (int nt = 0; nt < 2; ++nt) {
            int coll = wn * 32 + nt * 16 + lr;
#pragma unroll
            for (int r = 0; r < 4; ++r) {
                int rowl = wm * 32 + mt * 16 + kg * 4 + r;
                ev[mt][nt][r] = __expf(acc[mt][nt][r]);
                mk[mt][nt][r] = (ap[(size_t)rowl * NN + coll] & 0x8000u) != 0;
            }
        }
    // direct stats: row sums over this wave's 32-col slice -> slot bj*2+wn
    {
        int slot = bj * 2 + wn;
        float* Sp1 = Sp + (((size_t)b) * 16 + slot) * NN;
        float* Sp2 = Sp + (((size_t)BB + b) * 16 + slot) * NN;
#pragma unroll
        for (int mt = 0; mt < 2; ++mt) {
#pragma unroll
            for (int r = 0; r < 4; ++r) {
                float v1 = 0.f, v2 = 0.f;
#pragma unroll
                for (int nt = 0; nt < 2; ++nt) {
                    v2 += ev[mt][nt][r];
                    if (mk[mt][nt][r]) v1 += ev[mt][nt][r];
                }
#pragma unroll
                for (int off = 1; off < 16; off <<= 1) {
                    v1 += __shfl_xor(v1, off);
                    v2 += __shfl_xor(v2, off);
                }
                if (lr == 0) {
                    int rowl = wm * 32 + mt * 16 + kg * 4 + r;
                    Sp1[i0 + rowl] = v1;
                    Sp2[i0 + rowl] = v2;
                }
            }
        }
    }
    if (bi != bj) {
        // mirror stats: column sums (rows J, cols I wm-half) -> slot bi*2+wm
        int slot = bi * 2 + wm;
        float* Sp1 = Sp + (((size_t)b) * 16 + slot) * NN;
        float* Sp2 = Sp + (((size_t)BB + b) * 16 + slot) * NN;
#pragma unroll
        for (int nt = 0; nt < 2; ++nt) {
            float v1 = 0.f, v2 = 0.f;
#pragma unroll
            for (int mt = 0; mt < 2; ++mt)
#pragma unroll
                for (int r = 0; r < 4; ++r) {
                    v2 += ev[mt][nt][r];
                    if (mk[mt][nt][r]) v1 += ev[mt][nt][r];
                }
            v1 += __shfl_xor(v1, 16); v2 += __shfl_xor(v2, 16);
            v1 += __shfl_xor(v1, 32); v2 += __shfl_xor(v2, 32);
            if (kg == 0) {
                int rowm = j0 + wn * 32 + nt * 16 + lr;
                Sp1[rowm] = v1;
                Sp2[rowm] = v2;
            }
        }
        // mirror e-tile via LDS transpose
#pragma unroll
        for (int mt = 0; mt < 2; ++mt) {
#pragma unroll
            for (int nt = 0; nt < 2; ++nt) {
                int coll = wn * 32 + nt * 16 + lr;
#pragma unroll
                for (int r = 0; r < 4; ++r) {
                    int rowl = wm * 32 + mt * 16 + kg * 4 + r;
                    s_t[rowl * 66 + coll] = eh[mt][nt][r];
                }
            }
        }
        __syncthreads();
        int a = threadIdx.x >> 2, c0 = (threadIdx.x & 3) * 16;   // mirror row, col-seg
        ushort tmp[16];
#pragma unroll
        for (int q = 0; q < 16; ++q) tmp[q] = s_t[(c0 + q) * 66 + a];
        ushort* dst = eb + (size_t)(j0 + a) * NN + i0 + c0;
        *reinterpret_cast<bf16x8*>(dst) = *reinterpret_cast<const bf16x8*>(tmp);
        *reinterpret_cast<bf16x8*>(dst + 8) = *reinterpret_cast<const bf16x8*>(tmp + 8);
    }
}

// ---------------------------------------------------------------------------
// hprime + gate + NEXT-LAYER wtrans, fused. 16 i-rows per block (R13 exact:
// inline Sp re-reduce staging, 256 threads, 4 waves = path x col-half).
__global__ __launch_bounds__(256) void k_hprime(const ushort* __restrict__ e,
                                                const ushort* __restrict__ adjp,
                                                const ushort* __restrict__ hT_bf,
                                                const float* __restrict__ Sp,
                                                const float* __restrict__ gw,
                                                const float* __restrict__ gb,
                                                float* __restrict__ x,
                                                const ushort* __restrict__ Wwb2,
                                                const ushort* __restrict__ ATb2,
                                                const float* __restrict__ Wb2,
                                                int do_next,
                                                ushort* __restrict__ h2_bf,
                                                ushort* __restrict__ hA2_bf,
                                                ushort* __restrict__ hT2_bf) {
    __shared__ ushort s_att[2][2][4][16 * 40]; // [buf][path][sub][row*40+j] 20 KB
    __shared__ float s_C[2][NN];               // 4 KB (reciprocal denominators)
    __shared__ float s_h2[16][RST];            // 9.25 KB (path-1 hp tile)
    __shared__ float s_pz[4][16];
    __shared__ float s_px[2][16];
    // epilogue aliases (s_att dead after main loop): 2 x 16*168 ushorts = 10.5KB
    ushort* s_x  = &s_att[0][0][0][0];
    ushort* s_hh = s_x + 16 * 168;
    int b = blockIdx.y, i0 = blockIdx.x * 16;
    int tid = threadIdx.x;
    int w = tid >> 6, l = tid & 63;
    int p = w >> 1, half = w & 1;
    int ntb = half * 5, ncnt = half ? 4 : 5;
    int lr = l & 15, kg = l >> 4;
    int ai = tid >> 4, aj8 = (tid & 15) * 8;   // row, j-offset within 128-chunk
    int sub = aj8 >> 5, jj = aj8 & 31;
    const ushort* e_row = e + (size_t)b * NN * NN + (size_t)(i0 + ai) * NN;
    const ushort* p_row = adjp + (size_t)b * NN * NN + (size_t)(i0 + ai) * NN;
    const ushort* hTb = hT_bf + (size_t)b * DP * NN;

    // ---- issue ALL global loads up front (4 chunks x (e,adjp)) ----
    uint4 e_r[4], p_r[4];
#pragma unroll
    for (int c = 0; c < 4; ++c) {
        e_r[c] = *reinterpret_cast<const uint4*>(e_row + c * 128 + aj8);
        p_r[c] = *reinterpret_cast<const uint4*>(p_row + c * 128 + aj8);
    }
    float xq[5][4];
    if (p == 0) {
#pragma unroll
        for (int nt = 0; nt < 5; ++nt) {
            int col = (ntb + nt) * 16 + lr;
            bool ok = (nt < ncnt) && (col < DD);
#pragma unroll
            for (int r = 0; r < 4; ++r) {
                int row = kg * 4 + r;
                xq[nt][r] = ok ? x[((size_t)b * NN + i0 + row) * DD + col] : 0.f;
            }
        }
    }
    // stage reciprocal softmax denominators from 16 partial-sum slots
    {
        const float* Sp1 = Sp + ((size_t)b) * 16 * NN;
        const float* Sp2 = Sp + ((size_t)(BB + b)) * 16 * NN;
        for (int idx = tid; idx < NN; idx += 256) {
            float a1 = 0.f, a2s = 0.f;
#pragma unroll
            for (int jb = 0; jb < 16; ++jb) {
                a1 += Sp1[jb * NN + idx];
                a2s += Sp2[jb * NN + idx];
            }
            s_C[0][idx] = 1.0f / a1;
            s_C[1][idx] = 1.0f / a2s;
        }
    }

    auto build = [&](const uint4& ev4, const uint4& pv4, int cbase, int buf) {
        uint ew[4] = {ev4.x, ev4.y, ev4.z, ev4.w};
        uint pw[4] = {pv4.x, pv4.y, pv4.z, pv4.w};
        ushort o1[8], o2[8];
#pragma unroll
        for (int q = 0; q < 4; ++q) {
            float ev[2] = {h2f_bits((ushort)(ew[q] & 0xFFFFu)), h2f_bits((ushort)(ew[q] >> 16))};
            ushort hb[2] = {(ushort)(pw[q] & 0xFFFFu), (ushort)(pw[q] >> 16)};
#pragma unroll
            for (int c2 = 0; c2 < 2; ++c2) {
                int idx = q * 2 + c2;
                int jg = cbase + aj8 + idx;
                bool mask = (hb[c2] & 0x8000u) != 0;
                float a2 = h2f_bits((ushort)(hb[c2] & 0x7FFFu));
                float eexp = __expf(ev[c2]);
                float att1 = eexp * s_C[0][jg];
                float att2 = a2 * eexp * s_C[1][jg];
                o1[idx] = mask ? f2bf(att1) : (ushort)0;
                o2[idx] = f2bf(att2);
            }
        }
        uint4 w1, w2;
        w1.x = (uint)o1[0] | ((uint)o1[1] << 16); w1.y = (uint)o1[2] | ((uint)o1[3] << 16);
        w1.z = (uint)o1[4] | ((uint)o1[5] << 16); w1.w = (uint)o1[6] | ((uint)o1[7] << 16);
        w2.x = (uint)o2[0] | ((uint)o2[1] << 16); w2.y = (uint)o2[2] | ((uint)o2[3] << 16);
        w2.z = (uint)o2[4] | ((uint)o2[5] << 16); w2.w = (uint)o2[6] | ((uint)o2[7] << 16);
        *reinterpret_cast<uint4*>(&s_att[buf][0][sub][ai * 40 + jj]) = w1;
        *reinterpret_cast<uint4*>(&s_att[buf][1][sub][ai * 40 + jj]) = w2;
    };

    f32x4 acc[5];
#pragma unroll
    for (int nt = 0; nt < 5; ++nt) acc[nt] = (f32x4)(0.f);

    __syncthreads();           // s_C ready
    build(e_r[0], p_r[0], 0, 0);
    __syncthreads();
#pragma unroll
    for (int c = 0; c < 4; ++c) {
        int cb = c & 1, nb = cb ^ 1;
        if (c < 3) build(e_r[c + 1], p_r[c + 1], (c + 1) * 128, nb);
#pragma unroll
        for (int s4 = 0; s4 < 4; ++s4) {
            int j0 = c * 128 + s4 * 32;
            bf16x8 afr = *reinterpret_cast<const bf16x8*>(&s_att[cb][p][s4][lr * 40 + kg * 8]);
#pragma unroll
            for (int nt = 0; nt < 5; ++nt) {
                if (nt < ncnt) {
                    bf16x8 bfr = *reinterpret_cast<const bf16x8*>(
                        hTb + (size_t)((ntb + nt) * 16 + lr) * NN + j0 + kg * 8);
                    acc[nt] = __builtin_amdgcn_mfma_f32_16x16x32_bf16(afr, bfr, acc[nt], 0, 0, 0);
                }
            }
        }
        __syncthreads();
    }
    // relu + gate partials (wave-local complete j-sums)
    float z4[4] = {0.f, 0.f, 0.f, 0.f}, sx4[4] = {0.f, 0.f, 0.f, 0.f};
#pragma unroll
    for (int nt = 0; nt < 5; ++nt) {
        if (nt < ncnt) {
            int col = (ntb + nt) * 16 + lr;
            bool ok = col < DD;
            float g1 = ok ? gw[DD + col] : 0.f;
            float g0 = (ok && p == 0) ? gw[col] : 0.f;
#pragma unroll
            for (int r = 0; r < 4; ++r) {
                float hp = fmaxf(acc[nt][r], 0.f);
                acc[nt][r] = hp;
                z4[r] = fmaf(g1, hp, z4[r]);
                if (p == 0) sx4[r] = fmaf(g0, xq[nt][r], sx4[r]);
            }
        }
    }
#pragma unroll
    for (int off = 1; off < 16; off <<= 1) {
#pragma unroll
        for (int r = 0; r < 4; ++r) {
            z4[r] += __shfl_xor(z4[r], off);
            if (p == 0) sx4[r] += __shfl_xor(sx4[r], off);
        }
    }
    if (lr == 0) {
#pragma unroll
        for (int r = 0; r < 4; ++r) {
            s_pz[w][kg * 4 + r] = z4[r];
            if (p == 0) s_px[w][kg * 4 + r] = sx4[r];
        }
    }
    if (p == 1) {
#pragma unroll
        for (int nt = 0; nt < 5; ++nt) {
            if (nt < ncnt) {
                int col = (ntb + nt) * 16 + lr;
#pragma unroll
                for (int r = 0; r < 4; ++r)
                    s_h2[kg * 4 + r][col] = acc[nt][r];
            }
        }
    }
    __syncthreads();
    if (p == 0) {
        float gbv = gb[0];
#pragma unroll
        for (int r = 0; r < 4; ++r) {
            int row = kg * 4 + r;
            float sx = s_px[0][row] + s_px[1][row];
            float z1 = s_pz[0][row] + s_pz[1][row];
            float z2 = s_pz[2][row] + s_pz[3][row];
            float c1 = 1.f / (1.f + __expf(-(sx + z1 + gbv)));
            float c2 = 1.f / (1.f + __expf(-(sx + z2 + gbv)));
#pragma unroll
            for (int nt = 0; nt < 5; ++nt) {
                if (nt < ncnt) {
                    int col = (ntb + nt) * 16 + lr;
                    if (col < DD) {
                        float xnew = (c2 - c1) * xq[nt][r] + (1.f - c2) * s_h2[row][col]
                                   - (1.f - c1) * acc[nt][r];
                        size_t bn = (size_t)b * NN + i0 + row;
                        x[bn * DD + col] = xnew;
                        s_x[row * 168 + col] = f2bf(xnew);
                    }
                }
            }
        }
    } else if (do_next) {
        // zero-fill s_x pad cols 140..159 (16 rows x 20 cols = 320)
        for (int idx = tid - 128; idx < 320; idx += 128) {
            int row = idx / 20, col = DD + idx % 20;
            s_x[row * 168 + col] = 0;
        }
    }
    if (do_next) {
        __syncthreads();       // s_x complete
        int ntile = (w < 2) ? 3 : 2;
        f32x4 acc2[3];
#pragma unroll
        for (int q = 0; q < 3; ++q) acc2[q] = (f32x4)(0.f);
        // GEMM1: h = xnew @ Ww2^T (+Wb2)
        for (int f0 = 0; f0 < DP; f0 += 32) {
            bf16x8 a = *reinterpret_cast<const bf16x8*>(&s_x[lr * 168 + f0 + kg * 8]);
#pragma unroll
            for (int q = 0; q < 3; ++q) {
                if (q < ntile) {
                    int col = (w + q * 4) * 16 + lr;
                    bf16x8 bfr = *reinterpret_cast<const bf16x8*>(Wwb2 + (size_t)col * DP + f0 + kg * 8);
                    acc2[q] = __builtin_amdgcn_mfma_f32_16x16x32_bf16(a, bfr, acc2[q], 0, 0, 0);
                }
            }
        }
#pragma unroll
        for (int q = 0; q < 3; ++q) {
            if (q < ntile) {
                int col = (w + q * 4) * 16 + lr;
                float bias = col < DD ? Wb2[col] : 0.f;
#pragma unroll
                for (int r = 0; r < 4; ++r) {
                    int row = kg * 4 + r;
                    float v = col < DD ? acc2[q][r] + bias : 0.f;
                    ushort u = f2bf(v);
                    s_hh[row * 168 + col] = u;
                    h2_bf[((size_t)b * NN + i0 + row) * DP + col] = u;
                }
                acc2[q] = (f32x4)(0.f);
            }
        }
        __syncthreads();       // s_hh complete
        // GEMM2: hA = h @ A2
        for (int f0 = 0; f0 < DP; f0 += 32) {
            bf16x8 a = *reinterpret_cast<const bf16x8*>(&s_hh[lr * 168 + f0 + kg * 8]);
#pragma unroll
            for (int q = 0; q < 3; ++q) {
                if (q < ntile) {
                    int col = (w + q * 4) * 16 + lr;
                    bf16x8 bfr = *reinterpret_cast<const bf16x8*>(ATb2 + (size_t)col * DP + f0 + kg * 8);
                    acc2[q] = __builtin_amdgcn_mfma_f32_16x16x32_bf16(a, bfr, acc2[q], 0, 0, 0);
                }
            }
        }
#pragma unroll
        for (int q = 0; q < 3; ++q) {
            if (q < ntile) {
                int col = (w + q * 4) * 16 + lr;
#pragma unroll
                for (int r = 0; r < 4; ++r)
                    hA2_bf[((size_t)b * NN + i0 + kg * 4 + r) * DP + col] = f2bf(acc2[q][r]);
            }
        }
        // hT for next layer (16 columns i0..i0+16)
        if (tid < DP) {
            int d = tid;
            ushort tmp[16];
#pragma unroll
            for (int nn = 0; nn < 16; ++nn) tmp[nn] = s_hh[nn * 168 + d];
            ushort* dst = hT2_bf + ((size_t)b * DP + d) * NN + i0;
            *reinterpret_cast<bf16x8*>(dst) = *reinterpret_cast<const bf16x8*>(tmp);
            *reinterpret_cast<bf16x8*>(dst + 8) = *reinterpret_cast<const bf16x8*>(tmp + 8);
        }
    }
}

// ---------------------------------------------------------------------------
// readout (4-way n-split): Gp[b][ch][d] = sum_{n in chunk ch} x*valid.
// Was 1 block/batch with a 512-long serial fma chain; now 128 blocks x 128.
__global__ __launch_bounds__(256) void k_readout(const float* __restrict__ x,
                                                 const float* __restrict__ valid,
                                                 float* __restrict__ Gp) {
    int b = blockIdx.x >> 2, ch = blockIdx.x & 3;
    int t = threadIdx.x;
    if (t < DD) {
        float acc = 0.f;
        int n0 = ch * 128;
        for (int n = n0; n < n0 + 128; ++n)
            acc = fmaf(x[((size_t)b * NN + n) * DD + t], valid[b * NN + n], acc);
        Gp[((size_t)b * 4 + ch) * DD + t] = acc;
    }
}

// ---------------------------------------------------------------------------
// tiny MLP head: relu x3 + sigmoid (sums the 4 readout partials on load)
__global__ __launch_bounds__(128) void k_mlp(const float* __restrict__ Gp,
                                             const float* __restrict__ w0, const float* __restrict__ b0,
                                             const float* __restrict__ w1, const float* __restrict__ b1,
                                             const float* __restrict__ w2, const float* __restrict__ b2,
                                             const float* __restrict__ w3, const float* __restrict__ b3,
                                             float* __restrict__ out) {
    __shared__ float s0[DD];
    __shared__ float s1[DF];
    __shared__ float s2[DF];
    __shared__ float s_part[2];
    int b = blockIdx.x, t = threadIdx.x;
    for (int i = t; i < DD; i += 128)
        s0[i] = Gp[((size_t)b * 4 + 0) * DD + i] + Gp[((size_t)b * 4 + 1) * DD + i]
              + Gp[((size_t)b * 4 + 2) * DD + i] + Gp[((size_t)b * 4 + 3) * DD + i];
    __syncthreads();
    float acc = b0[t];
    for (int dd2 = 0; dd2 < DD; ++dd2) acc = fmaf(s0[dd2], w0[dd2 * DF + t], acc);
    s1[t] = fmaxf(acc, 0.f);
    __syncthreads();
    acc = b1[t];
    for (int dd2 = 0; dd2 < DF; ++dd2) acc = fmaf(s1[dd2], w1[dd2 * DF + t], acc);
    s2[t] = fmaxf(acc, 0.f);
    __syncthreads();
    acc = b2[t];
    for (int dd2 = 0; dd2 < DF; ++dd2) acc = fmaf(s2[dd2], w2[dd2 * DF + t], acc);
    float h3 = fmaxf(acc, 0.f);
    float p = h3 * w3[t];
#pragma unroll
    for (int off = 32; off > 0; off >>= 1) p += __shfl_down(p, off);
    if ((t & 63) == 0) s_part[t >> 6] = p;
    __syncthreads();
    if (t == 0) {
        float s = s_part[0] + s_part[1] + b3[0];
        out[b] = 1.f / (1.f + __expf(-s));
    }
}

// ---------------------------------------------------------------------------
extern "C" void kernel_launch(void* const* d_in, const int* in_sizes, int n_in,
                              void* d_out, int out_size, void* d_ws, size_t ws_size,
                              hipStream_t stream) {
    const float* chs   = (const float*)d_in[0];
    const float* adj1  = (const float*)d_in[1];
    const float* dist  = (const float*)d_in[2];
    const float* valid = (const float*)d_in[3];
    const float* We    = (const float*)d_in[4];
    const float* Ww    = (const float*)d_in[5];
    const float* Wb    = (const float*)d_in[6];
    const float* A     = (const float*)d_in[7];
    const float* gw    = (const float*)d_in[8];
    const float* gb    = (const float*)d_in[9];
    const float* mu    = (const float*)d_in[10];
    const float* dev   = (const float*)d_in[11];
    const float* w0    = (const float*)d_in[12];
    const float* b0    = (const float*)d_in[13];
    const float* w1    = (const float*)d_in[14];
    const float* b1    = (const float*)d_in[15];
    const float* w2    = (const float*)d_in[16];
    const float* b2    = (const float*)d_in[17];
    const float* w3    = (const float*)d_in[18];
    const float* b3    = (const float*)d_in[19];
    float* out = (float*)d_out;

    const size_t SX  = (size_t)BB * NN * DD;
    const size_t SNN = (size_t)BB * NN * NN;
    const size_t SBF = (size_t)BB * NN * DP;
    const size_t SSP = (size_t)2 * BB * 16 * NN;   // stats partials
    float* ws  = (float*)d_ws;
    float* x   = ws;
    float* Sp  = x + SX;
    float* Gp  = Sp + SSP;                         // 4*BB*DD readout partials
    ushort* hset0  = (ushort*)(Gp + (size_t)4 * BB * DD);
    ushort* hset1  = hset0 + 3 * SBF;             // h, hA, hT (set 1)
    ushort* x_bf   = hset1 + 3 * SBF;
    ushort* Wwb    = x_bf + SBF;
    ushort* ATb    = Wwb + (size_t)LL * DP * DP;
    ushort* adjp   = ATb + (size_t)LL * DP * DP;  // BB*NN*NN fp16 (signed)
    ushort* e_h    = adjp + SNN;                  // BB*NN*NN fp16

    k_prepa<<<SNN / 1024, 256, 0, stream>>>(adj1, dist, mu, dev, adjp);
    k_prepw<<<dim3(DP * DP / 256, LL), 256, 0, stream>>>(Ww, A, Wwb, ATb);
    k_embed<<<BB * NN / 32, 256, 0, stream>>>(chs, We, x, x_bf);

    // layer-0 transforms
    k_wtrans<<<BB * NN / 32, 256, 0, stream>>>(x_bf, Wwb, ATb, Wb,
                                               hset0, hset0 + SBF, hset0 + 2 * SBF);

    for (int k = 0; k < LL; ++k) {
        ushort* cur = (k & 1) ? hset1 : hset0;
        ushort* nxt = (k & 1) ? hset0 : hset1;
        int kn = (k < LL - 1) ? k + 1 : k;
        const float* gwk = gw + (size_t)k * 2 * DD;
        const float* gbk = gb + k;
        k_esym<<<dim3(36, BB), 256, 0, stream>>>(cur, cur + SBF, adjp, e_h, Sp);
        k_hprime<<<dim3(NN / 16, BB), 256, 0, stream>>>(
            e_h, adjp, cur + 2 * SBF, Sp, gwk, gbk, x,
            Wwb + (size_t)kn * DP * DP, ATb + (size_t)kn * DP * DP, Wb + (size_t)kn * DD,
            (k < LL - 1) ? 1 : 0,
            nxt, nxt + SBF, nxt + 2 * SBF);
    }

    k_readout<<<BB * 4, 256, 0, stream>>>(x, valid, Gp);
    k_mlp<<<BB, 128, 0, stream>>>(Gp, w0, b0, w1, b1, w2, b2, w3, b3, out);
}